// Round 2
// baseline (11432.825 us; speedup 1.0000x reference)
//
#include <hip/hip_runtime.h>

#define H 256
#define TILE 64
#define BK 16

// ---------------- degree / edge-weight prep ----------------
__global__ __launch_bounds__(256) void k_init_deg(float* deg, int N) {
    int i = blockIdx.x * 256 + threadIdx.x;
    if (i < N) deg[i] = 1.0f;
}

__global__ __launch_bounds__(256) void k_count_deg(const int* __restrict__ dst, float* deg, int E) {
    int i = blockIdx.x * 256 + threadIdx.x;
    if (i < E) atomicAdd(&deg[dst[i]], 1.0f);
}

__global__ __launch_bounds__(256) void k_finish_deg(const float* __restrict__ deg,
                                                    float* __restrict__ dinv,
                                                    float* __restrict__ selfw, int N) {
    int i = blockIdx.x * 256 + threadIdx.x;
    if (i < N) {
        float d = deg[i];
        dinv[i] = 1.0f / sqrtf(d);
        selfw[i] = 1.0f / d;
    }
}

__global__ __launch_bounds__(256) void k_edge_w(const int* __restrict__ src, const int* __restrict__ dst,
                                                const float* __restrict__ dinv, float* __restrict__ ew, int E) {
    int e = blockIdx.x * 256 + threadIdx.x;
    if (e < E) ew[e] = dinv[src[e]] * dinv[dst[e]];
}

// ---------------- aggregation (p = P @ xin, P = sym-norm adjacency + self loop) ----------------
// p[i][c] = xin[i][c] * selfw[i]   (self-loop term; p stride fixed at 256)
// shift = log2(D/4); sx = xin row stride
__global__ __launch_bounds__(256) void k_agg_init(const float* __restrict__ xin, const float* __restrict__ selfw,
                                                  float* __restrict__ p, long total, int shift, int sx) {
    long idx = (long)blockIdx.x * 256 + threadIdx.x;
    if (idx >= total) return;
    int row = (int)(idx >> shift);
    int c4 = (int)(idx & ((1 << shift) - 1)) << 2;
    float4 h4 = *(const float4*)(xin + (size_t)row * sx + c4);
    float s = selfw[row];
    float4 o = make_float4(h4.x * s, h4.y * s, h4.z * s, h4.w * s);
    *(float4*)(p + (size_t)row * 256 + c4) = o;
}

// p[dst] += xin[src] * ew[e]  via atomics; (D/4) lanes per edge, float4 per lane
__global__ __launch_bounds__(256) void k_agg_edges(const float* __restrict__ xin, const int* __restrict__ src,
                                                   const int* __restrict__ dst, const float* __restrict__ ew,
                                                   float* __restrict__ p, long total, int shift, int sx) {
    long idx = (long)blockIdx.x * 256 + threadIdx.x;
    if (idx >= total) return;
    int e = (int)(idx >> shift);
    int c4 = (int)(idx & ((1 << shift) - 1)) << 2;
    int s = src[e], d = dst[e];
    float w = ew[e];
    float4 h4 = *(const float4*)(xin + (size_t)s * sx + c4);
    float* ap = p + (size_t)d * 256 + c4;
    atomicAdd(ap + 0, h4.x * w);
    atomicAdd(ap + 1, h4.y * w);
    atomicAdd(ap + 2, h4.z * w);
    atomicAdd(ap + 3, h4.w * w);
}

// ---------------- fused GCN layer GEMM ----------------
// Out = relu(Pm @ Wc + bc) + X @ Wd + bd
// Block = 64 rows x 256 cols (ALL output cols -> in-place over Pm is safe).
// Pm stride 256 (K cols used), X stride SX (K cols). Out written to Pm's buffer, stride 256.
__global__ __launch_bounds__(512) void k_fused_gcn(const float* __restrict__ Pm, const float* __restrict__ X,
                                                   const float* __restrict__ Wc, const float* __restrict__ bc,
                                                   const float* __restrict__ Wd, const float* __restrict__ bd,
                                                   float* __restrict__ Out, int N, int K, int SX) {
    __shared__ float Ps[64][17];
    __shared__ float Xs[64][17];
    __shared__ float Wcs[BK][256];
    __shared__ float Wds[BK][256];
    const int tid = threadIdx.x;
    const int row0 = blockIdx.x * 64;

    const int ar = tid >> 3, ak = (tid & 7) << 1;   // A-tiles: row, k-pair
    const int kw = tid >> 5, cw = (tid & 31) << 3;  // W-tiles: k, col-octet
    const int tx = tid & 31, ty = tid >> 5;          // compute: tx->8 cols, ty->4 rows

    float accC[4][8] = {};
    float accD[4][8] = {};

    for (int k0 = 0; k0 < K; k0 += BK) {
        int arow = row0 + ar;
        float2 pv = make_float2(0.f, 0.f), xv = make_float2(0.f, 0.f);
        if (arow < N) {
            pv = *(const float2*)(Pm + (size_t)arow * 256 + k0 + ak);
            xv = *(const float2*)(X + (size_t)arow * SX + k0 + ak);
        }
        Ps[ar][ak] = pv.x; Ps[ar][ak + 1] = pv.y;
        Xs[ar][ak] = xv.x; Xs[ar][ak + 1] = xv.y;
        *(float4*)&Wcs[kw][cw]     = *(const float4*)(Wc + (size_t)(k0 + kw) * 256 + cw);
        *(float4*)&Wcs[kw][cw + 4] = *(const float4*)(Wc + (size_t)(k0 + kw) * 256 + cw + 4);
        *(float4*)&Wds[kw][cw]     = *(const float4*)(Wd + (size_t)(k0 + kw) * 256 + cw);
        *(float4*)&Wds[kw][cw + 4] = *(const float4*)(Wd + (size_t)(k0 + kw) * 256 + cw + 4);
        __syncthreads();
#pragma unroll
        for (int k = 0; k < BK; ++k) {
            float pr[4], xr[4];
#pragma unroll
            for (int i = 0; i < 4; ++i) {
                pr[i] = Ps[ty * 4 + i][k];
                xr[i] = Xs[ty * 4 + i][k];
            }
            float wc_[8], wd_[8];
            *(float4*)&wc_[0] = *(const float4*)&Wcs[k][tx * 8];
            *(float4*)&wc_[4] = *(const float4*)&Wcs[k][tx * 8 + 4];
            *(float4*)&wd_[0] = *(const float4*)&Wds[k][tx * 8];
            *(float4*)&wd_[4] = *(const float4*)&Wds[k][tx * 8 + 4];
#pragma unroll
            for (int i = 0; i < 4; ++i)
#pragma unroll
                for (int j = 0; j < 8; ++j) {
                    accC[i][j] += pr[i] * wc_[j];
                    accD[i][j] += xr[i] * wd_[j];
                }
        }
        __syncthreads();
    }

    float bcv[8], bdv[8];
    *(float4*)&bcv[0] = *(const float4*)(bc + tx * 8);
    *(float4*)&bcv[4] = *(const float4*)(bc + tx * 8 + 4);
    *(float4*)&bdv[0] = *(const float4*)(bd + tx * 8);
    *(float4*)&bdv[4] = *(const float4*)(bd + tx * 8 + 4);
#pragma unroll
    for (int i = 0; i < 4; ++i) {
        int r = row0 + ty * 4 + i;
        if (r >= N) continue;
        float o[8];
#pragma unroll
        for (int j = 0; j < 8; ++j)
            o[j] = fmaxf(accC[i][j] + bcv[j], 0.f) + accD[i][j] + bdv[j];
        *(float4*)(Out + (size_t)r * 256 + tx * 8)     = *(float4*)&o[0];
        *(float4*)(Out + (size_t)r * 256 + tx * 8 + 4) = *(float4*)&o[4];
    }
}

// ---------------- plain tiled GEMM with bias+relu (pattern layers) ----------------
// C[N x M] = A[N x K] @ W[K x M] + bias, optional relu. K%16==0, M%64==0.
__global__ __launch_bounds__(256) void k_gemm_ep(const float* __restrict__ A, const float* __restrict__ W,
                                                 float* __restrict__ C, int N, int K, int M,
                                                 const float* __restrict__ bias, int postrelu) {
    __shared__ float As[BK][TILE];
    __shared__ float Ws[BK][TILE];
    const int tid = threadIdx.x;
    const int row0 = blockIdx.y * TILE;
    const int col0 = blockIdx.x * TILE;
    const int tx = tid & 15, ty = tid >> 4;

    float acc[4][4] = {};

    const int ar = tid >> 2, ak = (tid & 3) << 2;
    const int wk = tid >> 4, wc = (tid & 15) << 2;

    for (int k0 = 0; k0 < K; k0 += BK) {
        float4 av = make_float4(0.f, 0.f, 0.f, 0.f);
        int arow = row0 + ar;
        if (arow < N) av = *(const float4*)(A + (size_t)arow * K + k0 + ak);
        As[ak + 0][ar] = av.x;
        As[ak + 1][ar] = av.y;
        As[ak + 2][ar] = av.z;
        As[ak + 3][ar] = av.w;
        *(float4*)&Ws[wk][wc] = *(const float4*)(W + (size_t)(k0 + wk) * M + col0 + wc);
        __syncthreads();
#pragma unroll
        for (int k = 0; k < BK; ++k) {
            float4 a4 = *(const float4*)&As[k][ty << 2];
            float4 b4 = *(const float4*)&Ws[k][tx << 2];
            float a_[4] = {a4.x, a4.y, a4.z, a4.w};
            float b_[4] = {b4.x, b4.y, b4.z, b4.w};
#pragma unroll
            for (int i = 0; i < 4; ++i)
#pragma unroll
                for (int j = 0; j < 4; ++j) acc[i][j] += a_[i] * b_[j];
        }
        __syncthreads();
    }

    const int c = col0 + (tx << 2);
    float4 bv = make_float4(0.f, 0.f, 0.f, 0.f);
    if (bias) bv = *(const float4*)(bias + c);
#pragma unroll
    for (int i = 0; i < 4; ++i) {
        int r = row0 + (ty << 2) + i;
        if (r >= N) continue;
        float4 v = make_float4(acc[i][0] + bv.x, acc[i][1] + bv.y, acc[i][2] + bv.z, acc[i][3] + bv.w);
        if (postrelu) {
            v.x = fmaxf(v.x, 0.f); v.y = fmaxf(v.y, 0.f);
            v.z = fmaxf(v.z, 0.f); v.w = fmaxf(v.w, 0.f);
        }
        *(float4*)(C + (size_t)r * M + c) = v;
    }
}

// ---------------- pooling (batch is sorted -> contiguous ranges) ----------------
__global__ void k_ranges(const int* __restrict__ batch, int N, int B, int* __restrict__ start,
                         float* __restrict__ countsf) {
    int b = threadIdx.x;
    if (b <= B) {
        int lo = 0, hi = N;
        while (lo < hi) {
            int mid = (lo + hi) >> 1;
            if (batch[mid] < b) lo = mid + 1; else hi = mid;
        }
        start[b] = lo;
    }
    __syncthreads();
    if (b < B) {
        int cnt = start[b + 1] - start[b];
        countsf[b] = (float)(cnt > 0 ? cnt : 1);
    }
}

// mean-pool one matrix (N x 256, stride 256) into out (B x 256)
__global__ __launch_bounds__(256) void k_pool1(const float* __restrict__ M_, const int* __restrict__ start,
                                               const float* __restrict__ countsf, float* __restrict__ out) {
    int b = blockIdx.x >> 2;
    int chunk = blockIdx.x & 3;
    int col = chunk * 64 + (threadIdx.x & 63);
    int stripe = threadIdx.x >> 6;
    int r0 = start[b], r1 = start[b + 1];
    float s = 0.f;
    for (int r = r0 + stripe; r < r1; r += 4) s += M_[(size_t)r * 256 + col];
    __shared__ float red[4][64];
    red[stripe][threadIdx.x & 63] = s;
    __syncthreads();
    if (stripe == 0) {
        int c = threadIdx.x & 63;
        float v = (red[0][c] + red[1][c] + red[2][c] + red[3][c]) / countsf[b];
        out[(size_t)b * 256 + col] = v;
    }
}

// ---------------- small (B=64 row) dense layers ----------------
__global__ __launch_bounds__(256) void k_small_gemm(const float* __restrict__ A, const float* __restrict__ W,
                                                    const float* __restrict__ bias, float* __restrict__ C,
                                                    int Brows, int K, int M, int relu) {
    int c = blockIdx.x * 64 + (threadIdx.x & 63);
    int r = blockIdx.y * 4 + (threadIdx.x >> 6);
    if (r >= Brows || c >= M) return;
    float s = bias ? bias[c] : 0.f;
    const float* a = A + (size_t)r * K;
    for (int k = 0; k < K; ++k) s += a[k] * W[(size_t)k * M + c];
    if (relu) s = fmaxf(s, 0.f);
    C[(size_t)r * M + c] = s;
}

__global__ __launch_bounds__(256) void k_combined(const float* __restrict__ ge, const float* __restrict__ se,
                                                  const float* __restrict__ te, const float* __restrict__ pe,
                                                  const float* __restrict__ type_emb, const int* __restrict__ type_idx,
                                                  float* __restrict__ comb) {
    int b = blockIdx.x;
    int t = threadIdx.x;  // 256
    float* out = comb + (size_t)b * 1280;
    out[t] = ge[(size_t)b * H + t];
    out[256 + t] = se[(size_t)b * H + t];
    out[512 + t] = te[(size_t)b * H + t];
    out[768 + t] = type_emb[(size_t)type_idx[b] * H + t];
    out[1024 + t] = pe[(size_t)b * H + t];
}

// ---------------- host launch ----------------
extern "C" void kernel_launch(void* const* d_in, const int* in_sizes, int n_in,
                              void* d_out, int out_size, void* d_ws, size_t ws_size,
                              hipStream_t stream) {
    const float* x   = (const float*)d_in[0];
    const int* ei    = (const int*)d_in[1];
    const int* batch = (const int*)d_in[2];
    const float* sf  = (const float*)d_in[3];
    const float* tf  = (const float*)d_in[4];
    const int* tidx  = (const int*)d_in[5];
    const float* temb = (const float*)d_in[6];
    const float *Ws1 = (const float*)d_in[7],  *bs1 = (const float*)d_in[8];
    const float *Ws2 = (const float*)d_in[9],  *bs2 = (const float*)d_in[10];
    const float *Wc1 = (const float*)d_in[11], *bc1 = (const float*)d_in[12];
    const float *Wc2 = (const float*)d_in[13], *bc2 = (const float*)d_in[14];
    const float *Wc3 = (const float*)d_in[15], *bc3 = (const float*)d_in[16];
    const float *Wd1 = (const float*)d_in[17], *bd1 = (const float*)d_in[18];
    const float *Wd2 = (const float*)d_in[19], *bd2 = (const float*)d_in[20];
    const float *Wd3 = (const float*)d_in[21], *bd3 = (const float*)d_in[22];
    const float *Wt1 = (const float*)d_in[23], *bt1 = (const float*)d_in[24];
    const float *Wt2 = (const float*)d_in[25], *bt2 = (const float*)d_in[26];
    const float *Wp1 = (const float*)d_in[27], *bp1 = (const float*)d_in[28];
    const float *Wp2 = (const float*)d_in[29], *bp2 = (const float*)d_in[30];
    const float *Wf1 = (const float*)d_in[31], *bf1 = (const float*)d_in[32];
    const float *Wf2 = (const float*)d_in[33], *bf2 = (const float*)d_in[34];
    const float *Wg  = (const float*)d_in[35], *bg  = (const float*)d_in[36];
    const float *Wtp = (const float*)d_in[37], *btp = (const float*)d_in[38];

    const int N = in_sizes[2];
    const int E = in_sizes[1] / 2;
    const int B = in_sizes[5];
    const int DIN = in_sizes[0] / N;       // 128
    const int DS = in_sizes[3] / B;        // 1024
    const int NG = in_sizes[36];           // 20
    const int* src = ei;
    const int* dst = ei + E;

    // workspace layout (floats): 2 big buffers + small stuff  (~211 MB total)
    float* ws = (float*)d_ws;
    size_t NB = (size_t)N * H;
    float* A = ws;           // N x 256
    float* Bb = A + NB;      // N x 256
    float* ew = Bb + NB;     // E
    float* deg = ew + E;
    float* dinv = deg + N;
    float* selfw = dinv + N;
    int* startp = (int*)(selfw + N);
    float* countsf = (float*)(startp + (B + 1));
    float* ge = countsf + B;
    float* pe = ge + (size_t)B * H;
    float* s1buf = pe + (size_t)B * H;
    float* sebuf = s1buf + (size_t)B * H;
    float* t1buf = sebuf + (size_t)B * H;
    float* tebuf = t1buf + (size_t)B * 128;
    float* comb = tebuf + (size_t)B * H;
    float* fhbuf = comb + (size_t)B * 1280;

    float* out_fused = (float*)d_out;                 // B x 256
    float* out_logits = out_fused + (size_t)B * H;    // B x NG
    float* out_tp = out_logits + (size_t)B * NG;      // B x 1

    dim3 blk(256);

    // degree + edge weights
    k_init_deg<<<dim3((N + 255) / 256), blk, 0, stream>>>(deg, N);
    k_count_deg<<<dim3((E + 255) / 256), blk, 0, stream>>>(dst, deg, E);
    k_finish_deg<<<dim3((N + 255) / 256), blk, 0, stream>>>(deg, dinv, selfw, N);
    k_edge_w<<<dim3((E + 255) / 256), blk, 0, stream>>>(src, dst, dinv, ew, E);

    const int nfb = (N + 63) / 64;  // fused-GEMM row blocks

    // ---- layer 1: xin = x (N x 128). p -> A (cols 0..127, stride 256). x1 -> A ----
    {
        long tot_n = (long)N * 32;  // D=128 -> 32 float4/row
        long tot_e = (long)E * 32;
        k_agg_init<<<dim3((unsigned)((tot_n + 255) / 256)), blk, 0, stream>>>(x, selfw, A, tot_n, 5, 128);
        k_agg_edges<<<dim3((unsigned)((tot_e + 255) / 256)), blk, 0, stream>>>(x, src, dst, ew, A, tot_e, 5, 128);
        k_fused_gcn<<<dim3(nfb), dim3(512), 0, stream>>>(A, x, Wc1, bc1, Wd1, bd1, A, N, 128, 128);
    }
    // ---- layer 2: xin = x1 (A). p -> Bb. x2 -> Bb ----
    {
        long tot_n = (long)N * 64;
        long tot_e = (long)E * 64;
        k_agg_init<<<dim3((unsigned)((tot_n + 255) / 256)), blk, 0, stream>>>(A, selfw, Bb, tot_n, 6, 256);
        k_agg_edges<<<dim3((unsigned)((tot_e + 255) / 256)), blk, 0, stream>>>(A, src, dst, ew, Bb, tot_e, 6, 256);
        k_fused_gcn<<<dim3(nfb), dim3(512), 0, stream>>>(Bb, A, Wc2, bc2, Wd2, bd2, Bb, N, 256, 256);
    }
    // ---- layer 3: xin = x2 (Bb). p -> A. x3 -> A ----
    {
        long tot_n = (long)N * 64;
        long tot_e = (long)E * 64;
        k_agg_init<<<dim3((unsigned)((tot_n + 255) / 256)), blk, 0, stream>>>(Bb, selfw, A, tot_n, 6, 256);
        k_agg_edges<<<dim3((unsigned)((tot_e + 255) / 256)), blk, 0, stream>>>(Bb, src, dst, ew, A, tot_e, 6, 256);
        k_fused_gcn<<<dim3(nfb), dim3(512), 0, stream>>>(A, Bb, Wc3, bc3, Wd3, bd3, A, N, 256, 256);
    }

    // ---- pooling ranges + ge from x3 (A) ----
    k_ranges<<<dim3(1), dim3(128), 0, stream>>>(batch, N, B, startp, countsf);
    k_pool1<<<dim3(B * 4), blk, 0, stream>>>(A, startp, countsf, ge);

    // ---- pattern detector: p1 = relu(x3@Wp1+bp1) -> Bb (N x 128); pat = relu(p1@Wp2+bp2) -> A ----
    k_gemm_ep<<<dim3(128 / 64, (N + 63) / 64), blk, 0, stream>>>(A, Wp1, Bb, N, 256, 128, bp1, 1);
    k_gemm_ep<<<dim3(H / 64, (N + 63) / 64), blk, 0, stream>>>(Bb, Wp2, A, N, 128, 256, bp2, 1);
    k_pool1<<<dim3(B * 4), blk, 0, stream>>>(A, startp, countsf, pe);

    // ---- small dense layers ----
    k_small_gemm<<<dim3(H / 64, (B + 3) / 4), blk, 0, stream>>>(sf, Ws1, bs1, s1buf, B, DS, H, 1);
    k_small_gemm<<<dim3(H / 64, (B + 3) / 4), blk, 0, stream>>>(s1buf, Ws2, bs2, sebuf, B, H, H, 0);
    k_small_gemm<<<dim3(2, (B + 3) / 4), blk, 0, stream>>>(tf, Wt1, bt1, t1buf, B, 5, 128, 1);
    k_small_gemm<<<dim3(H / 64, (B + 3) / 4), blk, 0, stream>>>(t1buf, Wt2, bt2, tebuf, B, 128, H, 0);
    k_combined<<<dim3(B), blk, 0, stream>>>(ge, sebuf, tebuf, pe, temb, tidx, comb);
    k_small_gemm<<<dim3(512 / 64, (B + 3) / 4), blk, 0, stream>>>(comb, Wf1, bf1, fhbuf, B, 1280, 512, 1);
    k_small_gemm<<<dim3(H / 64, (B + 3) / 4), blk, 0, stream>>>(fhbuf, Wf2, bf2, out_fused, B, 512, H, 0);
    k_small_gemm<<<dim3((NG + 63) / 64, (B + 3) / 4), blk, 0, stream>>>(out_fused, Wg, bg, out_logits, B, H, NG, 0);
    k_small_gemm<<<dim3(1, (B + 3) / 4), blk, 0, stream>>>(out_fused, Wtp, btp, out_tp, B, H, 1, 0);
}

// Round 3
// 3473.394 us; speedup vs baseline: 3.2915x; 3.2915x over previous
//
#include <hip/hip_runtime.h>

#define H 256
#define TILE 64
#define BK 16

// ---------------- CSR build ----------------
__global__ __launch_bounds__(256) void k_zero_i(int* p, int n) {
    int i = blockIdx.x * 256 + threadIdx.x;
    if (i < n) p[i] = 0;
}

__global__ __launch_bounds__(256) void k_count_deg_i(const int* __restrict__ dst, int* cnt, int E) {
    int i = blockIdx.x * 256 + threadIdx.x;
    if (i < E) atomicAdd(&cnt[dst[i]], 1);
}

// per-block inclusive scan of 256 counts
__global__ __launch_bounds__(256) void k_scan1(const int* __restrict__ cnt, int* __restrict__ partial,
                                               int* __restrict__ bsums, int N) {
    __shared__ int s[256];
    int t = threadIdx.x;
    int idx = blockIdx.x * 256 + t;
    int v = idx < N ? cnt[idx] : 0;
    s[t] = v;
    __syncthreads();
    for (int off = 1; off < 256; off <<= 1) {
        int add = (t >= off) ? s[t - off] : 0;
        __syncthreads();
        s[t] += add;
        __syncthreads();
    }
    if (idx < N) partial[idx] = s[t];
    if (t == 255) bsums[blockIdx.x] = s[t];
}

// single-block scan of block sums (nb <= 1024)
__global__ __launch_bounds__(1024) void k_scan2(int* bsums, int nb) {
    __shared__ int s[1024];
    int t = threadIdx.x;
    s[t] = (t < nb) ? bsums[t] : 0;
    __syncthreads();
    for (int off = 1; off < 1024; off <<= 1) {
        int add = (t >= off) ? s[t - off] : 0;
        __syncthreads();
        s[t] += add;
        __syncthreads();
    }
    if (t < nb) bsums[t] = s[t];
}

// rowptr[i+1] = partial[i] + offset; rowptr[0] = 0
__global__ __launch_bounds__(256) void k_scan3(const int* __restrict__ partial, const int* __restrict__ bsums,
                                               int* __restrict__ rowptr, int N) {
    int idx = blockIdx.x * 256 + threadIdx.x;
    if (idx < N) {
        int off = blockIdx.x > 0 ? bsums[blockIdx.x - 1] : 0;
        rowptr[idx + 1] = partial[idx] + off;
        if (idx == 0) rowptr[0] = 0;
    }
}

__global__ __launch_bounds__(256) void k_finish_deg_i(const int* __restrict__ cnt,
                                                      float* __restrict__ dinv,
                                                      float* __restrict__ selfw, int N) {
    int i = blockIdx.x * 256 + threadIdx.x;
    if (i < N) {
        float d = 1.0f + (float)cnt[i];
        dinv[i] = rsqrtf(d);
        selfw[i] = 1.0f / d;
    }
}

// scatter edges into CSR slots; weight = dinv[src]*dinv[dst]
__global__ __launch_bounds__(256) void k_scatter(const int* __restrict__ src, const int* __restrict__ dst,
                                                 const float* __restrict__ dinv, const int* __restrict__ rowptr,
                                                 int* __restrict__ fill, int* __restrict__ esrc,
                                                 float* __restrict__ ewt, int E) {
    int e = blockIdx.x * 256 + threadIdx.x;
    if (e >= E) return;
    int s = src[e], d = dst[e];
    int pos = rowptr[d] + atomicAdd(&fill[d], 1);
    esrc[pos] = s;
    ewt[pos] = dinv[s] * dinv[d];
}

// ---------------- CSR gather aggregation:  p = P @ xin  (P = sym-norm adj + self-loop) ----------------
// one 64-lane wave per destination node; D=256 (float4/lane). p stride 256.
__global__ __launch_bounds__(256) void k_gather4(const float* __restrict__ xin, const int* __restrict__ rowptr,
                                                 const int* __restrict__ esrc, const float* __restrict__ ewt,
                                                 const float* __restrict__ selfw, float* __restrict__ p,
                                                 int N, int SX) {
    int node = blockIdx.x * 4 + (threadIdx.x >> 6);
    if (node >= N) return;
    int c = (threadIdx.x & 63) << 2;
    float4 acc = *(const float4*)(xin + (size_t)node * SX + c);
    float sw = selfw[node];
    acc.x *= sw; acc.y *= sw; acc.z *= sw; acc.w *= sw;
    int j = rowptr[node], r1 = rowptr[node + 1];
    for (; j + 1 < r1; j += 2) {
        int s0 = esrc[j], s1 = esrc[j + 1];
        float w0 = ewt[j], w1 = ewt[j + 1];
        float4 a = *(const float4*)(xin + (size_t)s0 * SX + c);
        float4 b = *(const float4*)(xin + (size_t)s1 * SX + c);
        acc.x += a.x * w0 + b.x * w1;
        acc.y += a.y * w0 + b.y * w1;
        acc.z += a.z * w0 + b.z * w1;
        acc.w += a.w * w0 + b.w * w1;
    }
    if (j < r1) {
        int s0 = esrc[j];
        float w0 = ewt[j];
        float4 a = *(const float4*)(xin + (size_t)s0 * SX + c);
        acc.x += a.x * w0; acc.y += a.y * w0; acc.z += a.z * w0; acc.w += a.w * w0;
    }
    *(float4*)(p + (size_t)node * 256 + c) = acc;
}

// D=128 variant (float2/lane). p stride 256 (cols 0..127 used).
__global__ __launch_bounds__(256) void k_gather2(const float* __restrict__ xin, const int* __restrict__ rowptr,
                                                 const int* __restrict__ esrc, const float* __restrict__ ewt,
                                                 const float* __restrict__ selfw, float* __restrict__ p,
                                                 int N, int SX) {
    int node = blockIdx.x * 4 + (threadIdx.x >> 6);
    if (node >= N) return;
    int c = (threadIdx.x & 63) << 1;
    float2 acc = *(const float2*)(xin + (size_t)node * SX + c);
    float sw = selfw[node];
    acc.x *= sw; acc.y *= sw;
    int j = rowptr[node], r1 = rowptr[node + 1];
    for (; j + 1 < r1; j += 2) {
        int s0 = esrc[j], s1 = esrc[j + 1];
        float w0 = ewt[j], w1 = ewt[j + 1];
        float2 a = *(const float2*)(xin + (size_t)s0 * SX + c);
        float2 b = *(const float2*)(xin + (size_t)s1 * SX + c);
        acc.x += a.x * w0 + b.x * w1;
        acc.y += a.y * w0 + b.y * w1;
    }
    if (j < r1) {
        int s0 = esrc[j];
        float w0 = ewt[j];
        float2 a = *(const float2*)(xin + (size_t)s0 * SX + c);
        acc.x += a.x * w0; acc.y += a.y * w0;
    }
    *(float2*)(p + (size_t)node * 256 + c) = acc;
}

// ---------------- fused GCN layer GEMM ----------------
// Out = relu(Pm @ Wc + bc) + X @ Wd + bd
// Block = 64 rows x 256 cols (ALL output cols -> in-place over Pm is safe).
__global__ __launch_bounds__(512) void k_fused_gcn(const float* __restrict__ Pm, const float* __restrict__ X,
                                                   const float* __restrict__ Wc, const float* __restrict__ bc,
                                                   const float* __restrict__ Wd, const float* __restrict__ bd,
                                                   float* __restrict__ Out, int N, int K, int SX) {
    __shared__ float Ps[64][17];
    __shared__ float Xs[64][17];
    __shared__ float Wcs[BK][256];
    __shared__ float Wds[BK][256];
    const int tid = threadIdx.x;
    const int row0 = blockIdx.x * 64;

    const int ar = tid >> 3, ak = (tid & 7) << 1;
    const int kw = tid >> 5, cw = (tid & 31) << 3;
    const int tx = tid & 31, ty = tid >> 5;

    float accC[4][8] = {};
    float accD[4][8] = {};

    for (int k0 = 0; k0 < K; k0 += BK) {
        int arow = row0 + ar;
        float2 pv = make_float2(0.f, 0.f), xv = make_float2(0.f, 0.f);
        if (arow < N) {
            pv = *(const float2*)(Pm + (size_t)arow * 256 + k0 + ak);
            xv = *(const float2*)(X + (size_t)arow * SX + k0 + ak);
        }
        Ps[ar][ak] = pv.x; Ps[ar][ak + 1] = pv.y;
        Xs[ar][ak] = xv.x; Xs[ar][ak + 1] = xv.y;
        *(float4*)&Wcs[kw][cw]     = *(const float4*)(Wc + (size_t)(k0 + kw) * 256 + cw);
        *(float4*)&Wcs[kw][cw + 4] = *(const float4*)(Wc + (size_t)(k0 + kw) * 256 + cw + 4);
        *(float4*)&Wds[kw][cw]     = *(const float4*)(Wd + (size_t)(k0 + kw) * 256 + cw);
        *(float4*)&Wds[kw][cw + 4] = *(const float4*)(Wd + (size_t)(k0 + kw) * 256 + cw + 4);
        __syncthreads();
#pragma unroll
        for (int k = 0; k < BK; ++k) {
            float pr[4], xr[4];
#pragma unroll
            for (int i = 0; i < 4; ++i) {
                pr[i] = Ps[ty * 4 + i][k];
                xr[i] = Xs[ty * 4 + i][k];
            }
            float wc_[8], wd_[8];
            *(float4*)&wc_[0] = *(const float4*)&Wcs[k][tx * 8];
            *(float4*)&wc_[4] = *(const float4*)&Wcs[k][tx * 8 + 4];
            *(float4*)&wd_[0] = *(const float4*)&Wds[k][tx * 8];
            *(float4*)&wd_[4] = *(const float4*)&Wds[k][tx * 8 + 4];
#pragma unroll
            for (int i = 0; i < 4; ++i)
#pragma unroll
                for (int j = 0; j < 8; ++j) {
                    accC[i][j] += pr[i] * wc_[j];
                    accD[i][j] += xr[i] * wd_[j];
                }
        }
        __syncthreads();
    }

    float bcv[8], bdv[8];
    *(float4*)&bcv[0] = *(const float4*)(bc + tx * 8);
    *(float4*)&bcv[4] = *(const float4*)(bc + tx * 8 + 4);
    *(float4*)&bdv[0] = *(const float4*)(bd + tx * 8);
    *(float4*)&bdv[4] = *(const float4*)(bd + tx * 8 + 4);
#pragma unroll
    for (int i = 0; i < 4; ++i) {
        int r = row0 + ty * 4 + i;
        if (r >= N) continue;
        float o[8];
#pragma unroll
        for (int j = 0; j < 8; ++j)
            o[j] = fmaxf(accC[i][j] + bcv[j], 0.f) + accD[i][j] + bdv[j];
        *(float4*)(Out + (size_t)r * 256 + tx * 8)     = *(float4*)&o[0];
        *(float4*)(Out + (size_t)r * 256 + tx * 8 + 4) = *(float4*)&o[4];
    }
}

// ---------------- plain tiled GEMM with bias+relu (pattern layers) ----------------
__global__ __launch_bounds__(256) void k_gemm_ep(const float* __restrict__ A, const float* __restrict__ W,
                                                 float* __restrict__ C, int N, int K, int M,
                                                 const float* __restrict__ bias, int postrelu) {
    __shared__ float As[BK][TILE];
    __shared__ float Ws[BK][TILE];
    const int tid = threadIdx.x;
    const int row0 = blockIdx.y * TILE;
    const int col0 = blockIdx.x * TILE;
    const int tx = tid & 15, ty = tid >> 4;

    float acc[4][4] = {};

    const int ar = tid >> 2, ak = (tid & 3) << 2;
    const int wk = tid >> 4, wc = (tid & 15) << 2;

    for (int k0 = 0; k0 < K; k0 += BK) {
        float4 av = make_float4(0.f, 0.f, 0.f, 0.f);
        int arow = row0 + ar;
        if (arow < N) av = *(const float4*)(A + (size_t)arow * K + k0 + ak);
        As[ak + 0][ar] = av.x;
        As[ak + 1][ar] = av.y;
        As[ak + 2][ar] = av.z;
        As[ak + 3][ar] = av.w;
        *(float4*)&Ws[wk][wc] = *(const float4*)(W + (size_t)(k0 + wk) * M + col0 + wc);
        __syncthreads();
#pragma unroll
        for (int k = 0; k < BK; ++k) {
            float4 a4 = *(const float4*)&As[k][ty << 2];
            float4 b4 = *(const float4*)&Ws[k][tx << 2];
            float a_[4] = {a4.x, a4.y, a4.z, a4.w};
            float b_[4] = {b4.x, b4.y, b4.z, b4.w};
#pragma unroll
            for (int i = 0; i < 4; ++i)
#pragma unroll
                for (int j = 0; j < 4; ++j) acc[i][j] += a_[i] * b_[j];
        }
        __syncthreads();
    }

    const int c = col0 + (tx << 2);
    float4 bv = make_float4(0.f, 0.f, 0.f, 0.f);
    if (bias) bv = *(const float4*)(bias + c);
#pragma unroll
    for (int i = 0; i < 4; ++i) {
        int r = row0 + (ty << 2) + i;
        if (r >= N) continue;
        float4 v = make_float4(acc[i][0] + bv.x, acc[i][1] + bv.y, acc[i][2] + bv.z, acc[i][3] + bv.w);
        if (postrelu) {
            v.x = fmaxf(v.x, 0.f); v.y = fmaxf(v.y, 0.f);
            v.z = fmaxf(v.z, 0.f); v.w = fmaxf(v.w, 0.f);
        }
        *(float4*)(C + (size_t)r * M + c) = v;
    }
}

// ---------------- pooling ----------------
__global__ void k_ranges(const int* __restrict__ batch, int N, int B, int* __restrict__ start,
                         float* __restrict__ countsf) {
    int b = threadIdx.x;
    if (b <= B) {
        int lo = 0, hi = N;
        while (lo < hi) {
            int mid = (lo + hi) >> 1;
            if (batch[mid] < b) lo = mid + 1; else hi = mid;
        }
        start[b] = lo;
    }
    __syncthreads();
    if (b < B) {
        int cnt = start[b + 1] - start[b];
        countsf[b] = (float)(cnt > 0 ? cnt : 1);
    }
}

__global__ __launch_bounds__(256) void k_pool1(const float* __restrict__ M_, const int* __restrict__ start,
                                               const float* __restrict__ countsf, float* __restrict__ out) {
    int b = blockIdx.x >> 2;
    int chunk = blockIdx.x & 3;
    int col = chunk * 64 + (threadIdx.x & 63);
    int stripe = threadIdx.x >> 6;
    int r0 = start[b], r1 = start[b + 1];
    float s = 0.f;
    for (int r = r0 + stripe; r < r1; r += 4) s += M_[(size_t)r * 256 + col];
    __shared__ float red[4][64];
    red[stripe][threadIdx.x & 63] = s;
    __syncthreads();
    if (stripe == 0) {
        int c = threadIdx.x & 63;
        float v = (red[0][c] + red[1][c] + red[2][c] + red[3][c]) / countsf[b];
        out[(size_t)b * 256 + col] = v;
    }
}

// ---------------- small (B=64 row) dense layers ----------------
__global__ __launch_bounds__(256) void k_small_gemm(const float* __restrict__ A, const float* __restrict__ W,
                                                    const float* __restrict__ bias, float* __restrict__ C,
                                                    int Brows, int K, int M, int relu) {
    int c = blockIdx.x * 64 + (threadIdx.x & 63);
    int r = blockIdx.y * 4 + (threadIdx.x >> 6);
    if (r >= Brows || c >= M) return;
    float s = bias ? bias[c] : 0.f;
    const float* a = A + (size_t)r * K;
    for (int k = 0; k < K; ++k) s += a[k] * W[(size_t)k * M + c];
    if (relu) s = fmaxf(s, 0.f);
    C[(size_t)r * M + c] = s;
}

__global__ __launch_bounds__(256) void k_combined(const float* __restrict__ ge, const float* __restrict__ se,
                                                  const float* __restrict__ te, const float* __restrict__ pe,
                                                  const float* __restrict__ type_emb, const int* __restrict__ type_idx,
                                                  float* __restrict__ comb) {
    int b = blockIdx.x;
    int t = threadIdx.x;  // 256
    float* out = comb + (size_t)b * 1280;
    out[t] = ge[(size_t)b * H + t];
    out[256 + t] = se[(size_t)b * H + t];
    out[512 + t] = te[(size_t)b * H + t];
    out[768 + t] = type_emb[(size_t)type_idx[b] * H + t];
    out[1024 + t] = pe[(size_t)b * H + t];
}

// ---------------- host launch ----------------
extern "C" void kernel_launch(void* const* d_in, const int* in_sizes, int n_in,
                              void* d_out, int out_size, void* d_ws, size_t ws_size,
                              hipStream_t stream) {
    const float* x   = (const float*)d_in[0];
    const int* ei    = (const int*)d_in[1];
    const int* batch = (const int*)d_in[2];
    const float* sf  = (const float*)d_in[3];
    const float* tf  = (const float*)d_in[4];
    const int* tidx  = (const int*)d_in[5];
    const float* temb = (const float*)d_in[6];
    const float *Ws1 = (const float*)d_in[7],  *bs1 = (const float*)d_in[8];
    const float *Ws2 = (const float*)d_in[9],  *bs2 = (const float*)d_in[10];
    const float *Wc1 = (const float*)d_in[11], *bc1 = (const float*)d_in[12];
    const float *Wc2 = (const float*)d_in[13], *bc2 = (const float*)d_in[14];
    const float *Wc3 = (const float*)d_in[15], *bc3 = (const float*)d_in[16];
    const float *Wd1 = (const float*)d_in[17], *bd1 = (const float*)d_in[18];
    const float *Wd2 = (const float*)d_in[19], *bd2 = (const float*)d_in[20];
    const float *Wd3 = (const float*)d_in[21], *bd3 = (const float*)d_in[22];
    const float *Wt1 = (const float*)d_in[23], *bt1 = (const float*)d_in[24];
    const float *Wt2 = (const float*)d_in[25], *bt2 = (const float*)d_in[26];
    const float *Wp1 = (const float*)d_in[27], *bp1 = (const float*)d_in[28];
    const float *Wp2 = (const float*)d_in[29], *bp2 = (const float*)d_in[30];
    const float *Wf1 = (const float*)d_in[31], *bf1 = (const float*)d_in[32];
    const float *Wf2 = (const float*)d_in[33], *bf2 = (const float*)d_in[34];
    const float *Wg  = (const float*)d_in[35], *bg  = (const float*)d_in[36];
    const float *Wtp = (const float*)d_in[37], *btp = (const float*)d_in[38];

    const int N = in_sizes[2];
    const int E = in_sizes[1] / 2;
    const int B = in_sizes[5];
    const int DS = in_sizes[3] / B;        // 1024
    const int NG = in_sizes[36];           // 20
    const int* src = ei;
    const int* dst = ei + E;

    // workspace layout (floats/ints): ~215 MB
    float* ws = (float*)d_ws;
    size_t NB = (size_t)N * H;
    float* A  = ws;          // N x 256
    float* Bb = A + NB;      // N x 256
    int*   esrc = (int*)(Bb + NB);     // E
    float* ewt  = (float*)(esrc + E);  // E
    int*   cnt  = (int*)(ewt + E);     // N (also reused as 'partial' target? no - separate)
    int*   part = cnt + N;             // N
    int*   rowptr = part + N;          // N+1
    int*   fill = rowptr + (N + 1);    // N
    int*   bsums = fill + N;           // 1024
    float* dinv = (float*)(bsums + 1024);  // N
    float* selfw = dinv + N;               // N
    int*   startp = (int*)(selfw + N);     // B+1
    float* countsf = (float*)(startp + (B + 1));
    float* ge = countsf + B;
    float* pe = ge + (size_t)B * H;
    float* s1buf = pe + (size_t)B * H;
    float* sebuf = s1buf + (size_t)B * H;
    float* t1buf = sebuf + (size_t)B * H;
    float* tebuf = t1buf + (size_t)B * 128;
    float* comb = tebuf + (size_t)B * H;
    float* fhbuf = comb + (size_t)B * 1280;

    float* out_fused = (float*)d_out;                 // B x 256
    float* out_logits = out_fused + (size_t)B * H;    // B x NG
    float* out_tp = out_logits + (size_t)B * NG;      // B x 1

    dim3 blk(256);
    const int nbN = (N + 255) / 256;
    const int nbE = (E + 255) / 256;

    // ---- CSR build ----
    k_zero_i<<<dim3(nbN), blk, 0, stream>>>(cnt, N);
    k_zero_i<<<dim3(nbN), blk, 0, stream>>>(fill, N);
    k_count_deg_i<<<dim3(nbE), blk, 0, stream>>>(dst, cnt, E);
    k_scan1<<<dim3(nbN), blk, 0, stream>>>(cnt, part, bsums, N);
    k_scan2<<<dim3(1), dim3(1024), 0, stream>>>(bsums, nbN);
    k_scan3<<<dim3(nbN), blk, 0, stream>>>(part, bsums, rowptr, N);
    k_finish_deg_i<<<dim3(nbN), blk, 0, stream>>>(cnt, dinv, selfw, N);
    k_scatter<<<dim3(nbE), blk, 0, stream>>>(src, dst, dinv, rowptr, fill, esrc, ewt, E);

    const int nfb = (N + 63) / 64;      // fused-GEMM row blocks
    const int ngb = (N + 3) / 4;        // gather blocks (4 nodes/block)

    // ---- layer 1: xin = x (N x 128). p -> A (stride 256). x1 -> A ----
    k_gather2<<<dim3(ngb), blk, 0, stream>>>(x, rowptr, esrc, ewt, selfw, A, N, 128);
    k_fused_gcn<<<dim3(nfb), dim3(512), 0, stream>>>(A, x, Wc1, bc1, Wd1, bd1, A, N, 128, 128);
    // ---- layer 2: xin = x1 (A). p -> Bb. x2 -> Bb ----
    k_gather4<<<dim3(ngb), blk, 0, stream>>>(A, rowptr, esrc, ewt, selfw, Bb, N, 256);
    k_fused_gcn<<<dim3(nfb), dim3(512), 0, stream>>>(Bb, A, Wc2, bc2, Wd2, bd2, Bb, N, 256, 256);
    // ---- layer 3: xin = x2 (Bb). p -> A. x3 -> A ----
    k_gather4<<<dim3(ngb), blk, 0, stream>>>(Bb, rowptr, esrc, ewt, selfw, A, N, 256);
    k_fused_gcn<<<dim3(nfb), dim3(512), 0, stream>>>(A, Bb, Wc3, bc3, Wd3, bd3, A, N, 256, 256);

    // ---- pooling ranges + ge from x3 (A) ----
    k_ranges<<<dim3(1), dim3(128), 0, stream>>>(batch, N, B, startp, countsf);
    k_pool1<<<dim3(B * 4), blk, 0, stream>>>(A, startp, countsf, ge);

    // ---- pattern detector: p1 -> Bb (N x 128); pat -> A ----
    k_gemm_ep<<<dim3(128 / 64, (N + 63) / 64), blk, 0, stream>>>(A, Wp1, Bb, N, 256, 128, bp1, 1);
    k_gemm_ep<<<dim3(H / 64, (N + 63) / 64), blk, 0, stream>>>(Bb, Wp2, A, N, 128, 256, bp2, 1);
    k_pool1<<<dim3(B * 4), blk, 0, stream>>>(A, startp, countsf, pe);

    // ---- small dense layers ----
    k_small_gemm<<<dim3(H / 64, (B + 3) / 4), blk, 0, stream>>>(sf, Ws1, bs1, s1buf, B, DS, H, 1);
    k_small_gemm<<<dim3(H / 64, (B + 3) / 4), blk, 0, stream>>>(s1buf, Ws2, bs2, sebuf, B, H, H, 0);
    k_small_gemm<<<dim3(2, (B + 3) / 4), blk, 0, stream>>>(tf, Wt1, bt1, t1buf, B, 5, 128, 1);
    k_small_gemm<<<dim3(H / 64, (B + 3) / 4), blk, 0, stream>>>(t1buf, Wt2, bt2, tebuf, B, 128, H, 0);
    k_combined<<<dim3(B), blk, 0, stream>>>(ge, sebuf, tebuf, pe, temb, tidx, comb);
    k_small_gemm<<<dim3(512 / 64, (B + 3) / 4), blk, 0, stream>>>(comb, Wf1, bf1, fhbuf, B, 1280, 512, 1);
    k_small_gemm<<<dim3(H / 64, (B + 3) / 4), blk, 0, stream>>>(fhbuf, Wf2, bf2, out_fused, B, 512, H, 0);
    k_small_gemm<<<dim3((NG + 63) / 64, (B + 3) / 4), blk, 0, stream>>>(out_fused, Wg, bg, out_logits, B, H, NG, 0);
    k_small_gemm<<<dim3(1, (B + 3) / 4), blk, 0, stream>>>(out_fused, Wtp, btp, out_tp, B, H, 1, 0);
}

// Round 4
// 2304.180 us; speedup vs baseline: 4.9618x; 1.5074x over previous
//
#include <hip/hip_runtime.h>

#define H 256
#define LDK 40  // padded k-stride (halves): 80B rows -> <=2-way LDS bank aliasing (free)

typedef __attribute__((ext_vector_type(8))) short bf16x8;
typedef __attribute__((ext_vector_type(4))) float f32x4;

__device__ __forceinline__ float b2f(ushort h) {
    return __uint_as_float(((unsigned)h) << 16);
}
__device__ __forceinline__ ushort f2bf(float f) {
    unsigned u = __float_as_uint(f);
    unsigned r = (u + 0x7FFF + ((u >> 16) & 1)) >> 16;  // RNE
    return (ushort)r;
}

// ---------------- CSR build ----------------
__global__ __launch_bounds__(256) void k_zero_i(int* p, int n) {
    int i = blockIdx.x * 256 + threadIdx.x;
    if (i < n) p[i] = 0;
}

__global__ __launch_bounds__(256) void k_count_deg_i(const int* __restrict__ dst, int* cnt, int E) {
    int i = blockIdx.x * 256 + threadIdx.x;
    if (i < E) atomicAdd(&cnt[dst[i]], 1);
}

__global__ __launch_bounds__(256) void k_scan1(const int* __restrict__ cnt, int* __restrict__ partial,
                                               int* __restrict__ bsums, int N) {
    __shared__ int s[256];
    int t = threadIdx.x;
    int idx = blockIdx.x * 256 + t;
    int v = idx < N ? cnt[idx] : 0;
    s[t] = v;
    __syncthreads();
    for (int off = 1; off < 256; off <<= 1) {
        int add = (t >= off) ? s[t - off] : 0;
        __syncthreads();
        s[t] += add;
        __syncthreads();
    }
    if (idx < N) partial[idx] = s[t];
    if (t == 255) bsums[blockIdx.x] = s[t];
}

__global__ __launch_bounds__(1024) void k_scan2(int* bsums, int nb) {
    __shared__ int s[1024];
    int t = threadIdx.x;
    s[t] = (t < nb) ? bsums[t] : 0;
    __syncthreads();
    for (int off = 1; off < 1024; off <<= 1) {
        int add = (t >= off) ? s[t - off] : 0;
        __syncthreads();
        s[t] += add;
        __syncthreads();
    }
    if (t < nb) bsums[t] = s[t];
}

__global__ __launch_bounds__(256) void k_scan3(const int* __restrict__ partial, const int* __restrict__ bsums,
                                               int* __restrict__ rowptr, int N) {
    int idx = blockIdx.x * 256 + threadIdx.x;
    if (idx < N) {
        int off = blockIdx.x > 0 ? bsums[blockIdx.x - 1] : 0;
        rowptr[idx + 1] = partial[idx] + off;
        if (idx == 0) rowptr[0] = 0;
    }
}

__global__ __launch_bounds__(256) void k_finish_deg_i(const int* __restrict__ cnt,
                                                      float* __restrict__ dinv,
                                                      float* __restrict__ selfw, int N) {
    int i = blockIdx.x * 256 + threadIdx.x;
    if (i < N) {
        float d = 1.0f + (float)cnt[i];
        dinv[i] = rsqrtf(d);
        selfw[i] = 1.0f / d;
    }
}

__global__ __launch_bounds__(256) void k_scatter(const int* __restrict__ src, const int* __restrict__ dst,
                                                 const float* __restrict__ dinv, const int* __restrict__ rowptr,
                                                 int* __restrict__ fill, int* __restrict__ esrc,
                                                 float* __restrict__ ewt, int E) {
    int e = blockIdx.x * 256 + threadIdx.x;
    if (e >= E) return;
    int s = src[e], d = dst[e];
    int pos = rowptr[d] + atomicAdd(&fill[d], 1);
    esrc[pos] = s;
    ewt[pos] = dinv[s] * dinv[d];
}

// ---------------- conversions ----------------
__global__ __launch_bounds__(256) void k_cvt(const float* __restrict__ in, ushort* __restrict__ out, long n) {
    long i = (long)blockIdx.x * 256 + threadIdx.x;
    if (i < n) out[i] = f2bf(in[i]);
}

// Wt[m][k] = bf16(W[k][m]); W is K x M row-major
__global__ __launch_bounds__(256) void k_tcvt(const float* __restrict__ W, ushort* __restrict__ Wt,
                                              int K, int M) {
    int idx = blockIdx.x * 256 + threadIdx.x;
    if (idx >= K * M) return;
    int k = idx / M, m = idx - k * M;
    Wt[(size_t)m * K + k] = f2bf(W[idx]);
}

// ---------------- CSR gather (bf16 in, fp32 acc, bf16 out) ----------------
// D=256: 4 bf16/lane. p stride SP.
__global__ __launch_bounds__(256) void k_gather_b4(const ushort* __restrict__ xin, const int* __restrict__ rowptr,
                                                   const int* __restrict__ esrc, const float* __restrict__ ewt,
                                                   const float* __restrict__ selfw, ushort* __restrict__ p,
                                                   int N, int SX, int SP) {
    int node = blockIdx.x * 4 + (threadIdx.x >> 6);
    if (node >= N) return;
    int c = (threadIdx.x & 63) << 2;
    ushort4 h = *(const ushort4*)(xin + (size_t)node * SX + c);
    float sw = selfw[node];
    float a0 = b2f(h.x) * sw, a1 = b2f(h.y) * sw, a2 = b2f(h.z) * sw, a3 = b2f(h.w) * sw;
    int j = rowptr[node], r1 = rowptr[node + 1];
    for (; j + 1 < r1; j += 2) {
        int s0 = esrc[j], s1 = esrc[j + 1];
        float w0 = ewt[j], w1 = ewt[j + 1];
        ushort4 v0 = *(const ushort4*)(xin + (size_t)s0 * SX + c);
        ushort4 v1 = *(const ushort4*)(xin + (size_t)s1 * SX + c);
        a0 += b2f(v0.x) * w0 + b2f(v1.x) * w1;
        a1 += b2f(v0.y) * w0 + b2f(v1.y) * w1;
        a2 += b2f(v0.z) * w0 + b2f(v1.z) * w1;
        a3 += b2f(v0.w) * w0 + b2f(v1.w) * w1;
    }
    if (j < r1) {
        int s0 = esrc[j];
        float w0 = ewt[j];
        ushort4 v0 = *(const ushort4*)(xin + (size_t)s0 * SX + c);
        a0 += b2f(v0.x) * w0; a1 += b2f(v0.y) * w0; a2 += b2f(v0.z) * w0; a3 += b2f(v0.w) * w0;
    }
    ushort4 o;
    o.x = f2bf(a0); o.y = f2bf(a1); o.z = f2bf(a2); o.w = f2bf(a3);
    *(ushort4*)(p + (size_t)node * SP + c) = o;
}

// D=128: 2 bf16/lane
__global__ __launch_bounds__(256) void k_gather_b2(const ushort* __restrict__ xin, const int* __restrict__ rowptr,
                                                   const int* __restrict__ esrc, const float* __restrict__ ewt,
                                                   const float* __restrict__ selfw, ushort* __restrict__ p,
                                                   int N, int SX, int SP) {
    int node = blockIdx.x * 4 + (threadIdx.x >> 6);
    if (node >= N) return;
    int c = (threadIdx.x & 63) << 1;
    ushort2 h = *(const ushort2*)(xin + (size_t)node * SX + c);
    float sw = selfw[node];
    float a0 = b2f(h.x) * sw, a1 = b2f(h.y) * sw;
    int j = rowptr[node], r1 = rowptr[node + 1];
    for (; j + 1 < r1; j += 2) {
        int s0 = esrc[j], s1 = esrc[j + 1];
        float w0 = ewt[j], w1 = ewt[j + 1];
        ushort2 v0 = *(const ushort2*)(xin + (size_t)s0 * SX + c);
        ushort2 v1 = *(const ushort2*)(xin + (size_t)s1 * SX + c);
        a0 += b2f(v0.x) * w0 + b2f(v1.x) * w1;
        a1 += b2f(v0.y) * w0 + b2f(v1.y) * w1;
    }
    if (j < r1) {
        int s0 = esrc[j];
        float w0 = ewt[j];
        ushort2 v0 = *(const ushort2*)(xin + (size_t)s0 * SX + c);
        a0 += b2f(v0.x) * w0; a1 += b2f(v0.y) * w0;
    }
    ushort2 o;
    o.x = f2bf(a0); o.y = f2bf(a1);
    *(ushort2*)(p + (size_t)node * SP + c) = o;
}

// ---------------- fused dual-GEMM MFMA:  Out = relu(Pm@Wc + bc) + X@Wd + bd ----------------
// bf16 in / fp32 acc / bf16 out. Block: 64 rows x 256 cols, 4 waves (wave w -> cols 64w..).
// Wct/Wdt are W^T [256][K] bf16. Out stride 256. In-place over Pm safe (own rows only).
__global__ __launch_bounds__(256, 2) void k_fused_mfma(
    const ushort* __restrict__ Pm, const ushort* __restrict__ X,
    const ushort* __restrict__ Wct, const ushort* __restrict__ Wdt,
    const float* __restrict__ bc, const float* __restrict__ bd,
    ushort* __restrict__ Out, int N, int K, int SP, int SX) {
    __shared__ short Ps[64 * LDK];
    __shared__ short Xs[64 * LDK];
    __shared__ short Wcs[256 * LDK];
    __shared__ short Wds[256 * LDK];
    const int tid = threadIdx.x;
    const int wave = tid >> 6, lane = tid & 63;
    const int row0 = blockIdx.x * 64;

    f32x4 accC[4][4], accD[4][4];
#pragma unroll
    for (int i = 0; i < 4; ++i)
#pragma unroll
        for (int j = 0; j < 4; ++j) { accC[i][j] = (f32x4)0.f; accD[i][j] = (f32x4)0.f; }

    const int sr = tid >> 2, sc = (tid & 3) * 8;
    int grow = row0 + sr; if (grow > N - 1) grow = N - 1;
    const int m = lane & 15, kh = (lane >> 4) * 8;

    for (int k0 = 0; k0 < K; k0 += 32) {
        *(uint4*)&Ps[sr * LDK + sc] = *(const uint4*)(Pm + (size_t)grow * SP + k0 + sc);
        *(uint4*)&Xs[sr * LDK + sc] = *(const uint4*)(X + (size_t)grow * SX + k0 + sc);
#pragma unroll
        for (int p = 0; p < 4; ++p) {
            int col = p * 64 + (tid >> 2);
            *(uint4*)&Wcs[col * LDK + sc] = *(const uint4*)(Wct + (size_t)col * K + k0 + sc);
            *(uint4*)&Wds[col * LDK + sc] = *(const uint4*)(Wdt + (size_t)col * K + k0 + sc);
        }
        __syncthreads();
        bf16x8 aP[4], aX[4], bC[4], bD[4];
#pragma unroll
        for (int i = 0; i < 4; ++i) {
            aP[i] = *(bf16x8*)&Ps[(16 * i + m) * LDK + kh];
            aX[i] = *(bf16x8*)&Xs[(16 * i + m) * LDK + kh];
        }
#pragma unroll
        for (int j = 0; j < 4; ++j) {
            int c = wave * 64 + 16 * j + m;
            bC[j] = *(bf16x8*)&Wcs[c * LDK + kh];
            bD[j] = *(bf16x8*)&Wds[c * LDK + kh];
        }
#pragma unroll
        for (int i = 0; i < 4; ++i)
#pragma unroll
            for (int j = 0; j < 4; ++j) {
                accC[i][j] = __builtin_amdgcn_mfma_f32_16x16x32_bf16(aP[i], bC[j], accC[i][j], 0, 0, 0);
                accD[i][j] = __builtin_amdgcn_mfma_f32_16x16x32_bf16(aX[i], bD[j], accD[i][j], 0, 0, 0);
            }
        __syncthreads();
    }

    const int rq = (lane >> 4) * 4;
#pragma unroll
    for (int j = 0; j < 4; ++j) {
        int col = wave * 64 + 16 * j + m;
        float bcv = bc[col], bdv = bd[col];
#pragma unroll
        for (int i = 0; i < 4; ++i)
#pragma unroll
            for (int g = 0; g < 4; ++g) {
                int row = row0 + 16 * i + rq + g;
                if (row < N) {
                    float v = fmaxf(accC[i][j][g] + bcv, 0.f) + accD[i][j][g] + bdv;
                    Out[(size_t)row * 256 + col] = f2bf(v);
                }
            }
    }
}

// ---------------- single-GEMM MFMA:  Out = [relu](A@W + b) ----------------
// M in {128,256}; rows/block R = 16384/M; wave -> (row_off, col_off). Out stride M.
__global__ __launch_bounds__(256, 2) void k_gemm_mfma(
    const ushort* __restrict__ A, const ushort* __restrict__ Wt, const float* __restrict__ bias,
    ushort* __restrict__ Out, int N, int K, int M, int SA, int dorelu) {
    __shared__ short As[128 * LDK];
    __shared__ short Wls[256 * LDK];
    const int tid = threadIdx.x;
    const int wave = tid >> 6, lane = tid & 63;
    const int MW = M >> 6;          // 2 or 4
    const int R = 16384 / M;        // 128 or 64
    const int row0 = blockIdx.x * R;
    const int row_off = (wave / MW) * 64, col_off = (wave % MW) * 64;

    f32x4 acc[4][4];
#pragma unroll
    for (int i = 0; i < 4; ++i)
#pragma unroll
        for (int j = 0; j < 4; ++j) acc[i][j] = (f32x4)0.f;

    const int m = lane & 15, kh = (lane >> 4) * 8, sc = (tid & 3) * 8;

    for (int k0 = 0; k0 < K; k0 += 32) {
        for (int c = tid; c < R * 4; c += 256) {
            int r = c >> 2, ck = (c & 3) * 8;
            int gr = row0 + r; if (gr > N - 1) gr = N - 1;
            *(uint4*)&As[r * LDK + ck] = *(const uint4*)(A + (size_t)gr * SA + k0 + ck);
        }
        for (int p = 0; p < MW; ++p) {
            int col = p * 64 + (tid >> 2);
            *(uint4*)&Wls[col * LDK + sc] = *(const uint4*)(Wt + (size_t)col * K + k0 + sc);
        }
        __syncthreads();
        bf16x8 af[4], bf[4];
#pragma unroll
        for (int i = 0; i < 4; ++i) af[i] = *(bf16x8*)&As[(row_off + 16 * i + m) * LDK + kh];
#pragma unroll
        for (int j = 0; j < 4; ++j) bf[j] = *(bf16x8*)&Wls[(col_off + 16 * j + m) * LDK + kh];
#pragma unroll
        for (int i = 0; i < 4; ++i)
#pragma unroll
            for (int j = 0; j < 4; ++j)
                acc[i][j] = __builtin_amdgcn_mfma_f32_16x16x32_bf16(af[i], bf[j], acc[i][j], 0, 0, 0);
        __syncthreads();
    }

    const int rq = (lane >> 4) * 4;
#pragma unroll
    for (int j = 0; j < 4; ++j) {
        int col = col_off + 16 * j + m;
        float bv = bias[col];
#pragma unroll
        for (int i = 0; i < 4; ++i)
#pragma unroll
            for (int g = 0; g < 4; ++g) {
                int row = row0 + row_off + 16 * i + rq + g;
                if (row < N) {
                    float v = acc[i][j][g] + bv;
                    if (dorelu) v = fmaxf(v, 0.f);
                    Out[(size_t)row * M + col] = f2bf(v);
                }
            }
    }
}

// ---------------- pooling ----------------
__global__ void k_ranges(const int* __restrict__ batch, int N, int B, int* __restrict__ start,
                         float* __restrict__ countsf) {
    int b = threadIdx.x;
    if (b <= B) {
        int lo = 0, hi = N;
        while (lo < hi) {
            int mid = (lo + hi) >> 1;
            if (batch[mid] < b) lo = mid + 1; else hi = mid;
        }
        start[b] = lo;
    }
    __syncthreads();
    if (b < B) {
        int cnt = start[b + 1] - start[b];
        countsf[b] = (float)(cnt > 0 ? cnt : 1);
    }
}

// mean-pool bf16 (N x 256, stride 256) -> fp32 out (B x 256)
__global__ __launch_bounds__(256) void k_pool1b(const ushort* __restrict__ M_, const int* __restrict__ start,
                                                const float* __restrict__ countsf, float* __restrict__ out) {
    int b = blockIdx.x >> 2;
    int chunk = blockIdx.x & 3;
    int col = chunk * 64 + (threadIdx.x & 63);
    int stripe = threadIdx.x >> 6;
    int r0 = start[b], r1 = start[b + 1];
    float s = 0.f;
    for (int r = r0 + stripe; r < r1; r += 4) s += b2f(M_[(size_t)r * 256 + col]);
    __shared__ float red[4][64];
    red[stripe][threadIdx.x & 63] = s;
    __syncthreads();
    if (stripe == 0) {
        int c = threadIdx.x & 63;
        float v = (red[0][c] + red[1][c] + red[2][c] + red[3][c]) / countsf[b];
        out[(size_t)b * 256 + col] = v;
    }
}

// ---------------- small (B=64 row) fp32 dense layers ----------------
__global__ __launch_bounds__(256) void k_small_gemm(const float* __restrict__ A, const float* __restrict__ W,
                                                    const float* __restrict__ bias, float* __restrict__ C,
                                                    int Brows, int K, int M, int relu) {
    int c = blockIdx.x * 64 + (threadIdx.x & 63);
    int r = blockIdx.y * 4 + (threadIdx.x >> 6);
    if (r >= Brows || c >= M) return;
    float s = bias ? bias[c] : 0.f;
    const float* a = A + (size_t)r * K;
    for (int k = 0; k < K; ++k) s += a[k] * W[(size_t)k * M + c];
    if (relu) s = fmaxf(s, 0.f);
    C[(size_t)r * M + c] = s;
}

__global__ __launch_bounds__(256) void k_combined(const float* __restrict__ ge, const float* __restrict__ se,
                                                  const float* __restrict__ te, const float* __restrict__ pe,
                                                  const float* __restrict__ type_emb, const int* __restrict__ type_idx,
                                                  float* __restrict__ comb) {
    int b = blockIdx.x;
    int t = threadIdx.x;  // 256
    float* out = comb + (size_t)b * 1280;
    out[t] = ge[(size_t)b * H + t];
    out[256 + t] = se[(size_t)b * H + t];
    out[512 + t] = te[(size_t)b * H + t];
    out[768 + t] = type_emb[(size_t)type_idx[b] * H + t];
    out[1024 + t] = pe[(size_t)b * H + t];
}

// ---------------- host launch ----------------
extern "C" void kernel_launch(void* const* d_in, const int* in_sizes, int n_in,
                              void* d_out, int out_size, void* d_ws, size_t ws_size,
                              hipStream_t stream) {
    const float* x   = (const float*)d_in[0];
    const int* ei    = (const int*)d_in[1];
    const int* batch = (const int*)d_in[2];
    const float* sf  = (const float*)d_in[3];
    const float* tf  = (const float*)d_in[4];
    const int* tidx  = (const int*)d_in[5];
    const float* temb = (const float*)d_in[6];
    const float *Ws1 = (const float*)d_in[7],  *bs1 = (const float*)d_in[8];
    const float *Ws2 = (const float*)d_in[9],  *bs2 = (const float*)d_in[10];
    const float *Wc1 = (const float*)d_in[11], *bc1 = (const float*)d_in[12];
    const float *Wc2 = (const float*)d_in[13], *bc2 = (const float*)d_in[14];
    const float *Wc3 = (const float*)d_in[15], *bc3 = (const float*)d_in[16];
    const float *Wd1 = (const float*)d_in[17], *bd1 = (const float*)d_in[18];
    const float *Wd2 = (const float*)d_in[19], *bd2 = (const float*)d_in[20];
    const float *Wd3 = (const float*)d_in[21], *bd3 = (const float*)d_in[22];
    const float *Wt1 = (const float*)d_in[23], *bt1 = (const float*)d_in[24];
    const float *Wt2 = (const float*)d_in[25], *bt2 = (const float*)d_in[26];
    const float *Wp1 = (const float*)d_in[27], *bp1 = (const float*)d_in[28];
    const float *Wp2 = (const float*)d_in[29], *bp2 = (const float*)d_in[30];
    const float *Wf1 = (const float*)d_in[31], *bf1 = (const float*)d_in[32];
    const float *Wf2 = (const float*)d_in[33], *bf2 = (const float*)d_in[34];
    const float *Wg  = (const float*)d_in[35], *bg  = (const float*)d_in[36];
    const float *Wtp = (const float*)d_in[37], *btp = (const float*)d_in[38];

    const int N = in_sizes[2];
    const int E = in_sizes[1] / 2;
    const int B = in_sizes[5];
    const int DS = in_sizes[3] / B;        // 1024
    const int NG = in_sizes[36];           // 20
    const int* src = ei;
    const int* dst = ei + E;

    // ---- workspace layout (bytes; big 16B-aligned buffers first) ----
    char* w = (char*)d_ws;
    ushort* A   = (ushort*)w;              w += (size_t)N * 256 * 2;   // 51.2 MB
    ushort* Bb  = (ushort*)w;              w += (size_t)N * 256 * 2;   // 51.2 MB
    ushort* xh  = (ushort*)w;              w += (size_t)N * 128 * 2;   // 25.6 MB
    ushort* Wc1t = (ushort*)w;             w += 128 * 256 * 2;
    ushort* Wd1t = (ushort*)w;             w += 128 * 256 * 2;
    ushort* Wc2t = (ushort*)w;             w += 256 * 256 * 2;
    ushort* Wd2t = (ushort*)w;             w += 256 * 256 * 2;
    ushort* Wc3t = (ushort*)w;             w += 256 * 256 * 2;
    ushort* Wd3t = (ushort*)w;             w += 256 * 256 * 2;
    ushort* Wp1t = (ushort*)w;             w += 256 * 128 * 2;
    ushort* Wp2t = (ushort*)w;             w += 128 * 256 * 2;
    int* esrc   = (int*)w;                 w += (size_t)E * 4;
    float* ewt  = (float*)w;               w += (size_t)E * 4;
    int* cnt    = (int*)w;                 w += (size_t)N * 4;
    int* part   = (int*)w;                 w += (size_t)N * 4;
    int* rowptr = (int*)w;                 w += (size_t)(N + 1) * 4;
    int* fill   = (int*)w;                 w += (size_t)N * 4;
    int* bsums  = (int*)w;                 w += 1024 * 4;
    float* dinv = (float*)w;               w += (size_t)N * 4;
    float* selfw = (float*)w;              w += (size_t)N * 4;
    int* startp = (int*)w;                 w += (B + 1) * 4;
    float* countsf = (float*)w;            w += B * 4;
    float* ge = (float*)w;                 w += B * 256 * 4;
    float* pe = (float*)w;                 w += B * 256 * 4;
    float* s1buf = (float*)w;              w += B * 256 * 4;
    float* sebuf = (float*)w;              w += B * 256 * 4;
    float* t1buf = (float*)w;              w += B * 128 * 4;
    float* tebuf = (float*)w;              w += B * 256 * 4;
    float* comb = (float*)w;               w += B * 1280 * 4;
    float* fhbuf = (float*)w;              w += B * 512 * 4;

    float* out_fused = (float*)d_out;                 // B x 256
    float* out_logits = out_fused + (size_t)B * H;    // B x NG
    float* out_tp = out_logits + (size_t)B * NG;      // B x 1

    dim3 blk(256);
    const int nbN = (N + 255) / 256;
    const int nbE = (E + 255) / 256;

    // ---- CSR build ----
    k_zero_i<<<dim3(nbN), blk, 0, stream>>>(cnt, N);
    k_zero_i<<<dim3(nbN), blk, 0, stream>>>(fill, N);
    k_count_deg_i<<<dim3(nbE), blk, 0, stream>>>(dst, cnt, E);
    k_scan1<<<dim3(nbN), blk, 0, stream>>>(cnt, part, bsums, N);
    k_scan2<<<dim3(1), dim3(1024), 0, stream>>>(bsums, nbN);
    k_scan3<<<dim3(nbN), blk, 0, stream>>>(part, bsums, rowptr, N);
    k_finish_deg_i<<<dim3(nbN), blk, 0, stream>>>(cnt, dinv, selfw, N);
    k_scatter<<<dim3(nbE), blk, 0, stream>>>(src, dst, dinv, rowptr, fill, esrc, ewt, E);

    // ---- conversions ----
    {
        long nx = (long)N * 128;
        k_cvt<<<dim3((unsigned)((nx + 255) / 256)), blk, 0, stream>>>(x, xh, nx);
        k_tcvt<<<dim3((128 * 256 + 255) / 256), blk, 0, stream>>>(Wc1, Wc1t, 128, 256);
        k_tcvt<<<dim3((128 * 256 + 255) / 256), blk, 0, stream>>>(Wd1, Wd1t, 128, 256);
        k_tcvt<<<dim3((256 * 256 + 255) / 256), blk, 0, stream>>>(Wc2, Wc2t, 256, 256);
        k_tcvt<<<dim3((256 * 256 + 255) / 256), blk, 0, stream>>>(Wd2, Wd2t, 256, 256);
        k_tcvt<<<dim3((256 * 256 + 255) / 256), blk, 0, stream>>>(Wc3, Wc3t, 256, 256);
        k_tcvt<<<dim3((256 * 256 + 255) / 256), blk, 0, stream>>>(Wd3, Wd3t, 256, 256);
        k_tcvt<<<dim3((256 * 128 + 255) / 256), blk, 0, stream>>>(Wp1, Wp1t, 256, 128);
        k_tcvt<<<dim3((128 * 256 + 255) / 256), blk, 0, stream>>>(Wp2, Wp2t, 128, 256);
    }

    const int ngb = (N + 3) / 4;        // gather blocks (4 nodes/block)
    const int nfb = (N + 63) / 64;      // dual-MFMA row blocks

    // ---- layer 1: gather(xh,128) -> A(s128); fused(A s128, xh s128, K=128) -> Bb = x1 ----
    k_gather_b2<<<dim3(ngb), blk, 0, stream>>>(xh, rowptr, esrc, ewt, selfw, A, N, 128, 128);
    k_fused_mfma<<<dim3(nfb), blk, 0, stream>>>(A, xh, Wc1t, Wd1t, bc1, bd1, Bb, N, 128, 128, 128);
    // ---- layer 2: gather(Bb) -> A; fused(A, Bb, K=256) -> A = x2 ----
    k_gather_b4<<<dim3(ngb), blk, 0, stream>>>(Bb, rowptr, esrc, ewt, selfw, A, N, 256, 256);
    k_fused_mfma<<<dim3(nfb), blk, 0, stream>>>(A, Bb, Wc2t, Wd2t, bc2, bd2, A, N, 256, 256, 256);
    // ---- layer 3: gather(A) -> Bb; fused(Bb, A, K=256) -> Bb = x3 ----
    k_gather_b4<<<dim3(ngb), blk, 0, stream>>>(A, rowptr, esrc, ewt, selfw, Bb, N, 256, 256);
    k_fused_mfma<<<dim3(nfb), blk, 0, stream>>>(Bb, A, Wc3t, Wd3t, bc3, bd3, Bb, N, 256, 256, 256);

    // ---- pooling ranges + ge from x3 (Bb) ----
    k_ranges<<<dim3(1), dim3(128), 0, stream>>>(batch, N, B, startp, countsf);
    k_pool1b<<<dim3(B * 4), blk, 0, stream>>>(Bb, startp, countsf, ge);

    // ---- pattern: p1 = relu(x3@Wp1) -> A (s128, M=128); pat = relu(p1@Wp2) -> Bb (M=256) ----
    k_gemm_mfma<<<dim3((N + 127) / 128), blk, 0, stream>>>(Bb, Wp1t, bp1, A, N, 256, 128, 256, 1);
    k_gemm_mfma<<<dim3((N + 63) / 64), blk, 0, stream>>>(A, Wp2t, bp2, Bb, N, 128, 256, 128, 1);
    k_pool1b<<<dim3(B * 4), blk, 0, stream>>>(Bb, startp, countsf, pe);

    // ---- small fp32 dense layers (post-pooling path stays fp32 for accuracy) ----
    k_small_gemm<<<dim3(H / 64, (B + 3) / 4), blk, 0, stream>>>(sf, Ws1, bs1, s1buf, B, DS, H, 1);
    k_small_gemm<<<dim3(H / 64, (B + 3) / 4), blk, 0, stream>>>(s1buf, Ws2, bs2, sebuf, B, H, H, 0);
    k_small_gemm<<<dim3(2, (B + 3) / 4), blk, 0, stream>>>(tf, Wt1, bt1, t1buf, B, 5, 128, 1);
    k_small_gemm<<<dim3(H / 64, (B + 3) / 4), blk, 0, stream>>>(t1buf, Wt2, bt2, tebuf, B, 128, H, 0);
    k_combined<<<dim3(B), blk, 0, stream>>>(ge, sebuf, tebuf, pe, temb, tidx, comb);
    k_small_gemm<<<dim3(512 / 64, (B + 3) / 4), blk, 0, stream>>>(comb, Wf1, bf1, fhbuf, B, 1280, 512, 1);
    k_small_gemm<<<dim3(H / 64, (B + 3) / 4), blk, 0, stream>>>(fhbuf, Wf2, bf2, out_fused, B, 512, H, 0);
    k_small_gemm<<<dim3((NG + 63) / 64, (B + 3) / 4), blk, 0, stream>>>(out_fused, Wg, bg, out_logits, B, H, NG, 0);
    k_small_gemm<<<dim3(1, (B + 3) / 4), blk, 0, stream>>>(out_fused, Wtp, btp, out_tp, B, H, 1, 0);
}

// Round 5
// 1288.982 us; speedup vs baseline: 8.8697x; 1.7876x over previous
//
#include <hip/hip_runtime.h>

#define H 256
#define LDK 40  // padded k-stride (halves): 80B rows -> <=2-way LDS bank aliasing (free)

typedef __attribute__((ext_vector_type(8))) short bf16x8;
typedef __attribute__((ext_vector_type(4))) float f32x4;

__device__ __forceinline__ float b2f(ushort h) {
    return __uint_as_float(((unsigned)h) << 16);
}
__device__ __forceinline__ ushort f2bf(float f) {
    unsigned u = __float_as_uint(f);
    unsigned r = (u + 0x7FFF + ((u >> 16) & 1)) >> 16;  // RNE
    return (ushort)r;
}

// ---------------- CSR build ----------------
__global__ __launch_bounds__(256) void k_zero_i(int* p, int n) {
    int i = blockIdx.x * 256 + threadIdx.x;
    if (i < n) p[i] = 0;
}

__global__ __launch_bounds__(256) void k_count_deg_i(const int* __restrict__ dst, int* cnt, int E) {
    int i = blockIdx.x * 256 + threadIdx.x;
    if (i < E) atomicAdd(&cnt[dst[i]], 1);
}

__global__ __launch_bounds__(256) void k_scan1(const int* __restrict__ cnt, int* __restrict__ partial,
                                               int* __restrict__ bsums, int N) {
    __shared__ int s[256];
    int t = threadIdx.x;
    int idx = blockIdx.x * 256 + t;
    int v = idx < N ? cnt[idx] : 0;
    s[t] = v;
    __syncthreads();
    for (int off = 1; off < 256; off <<= 1) {
        int add = (t >= off) ? s[t - off] : 0;
        __syncthreads();
        s[t] += add;
        __syncthreads();
    }
    if (idx < N) partial[idx] = s[t];
    if (t == 255) bsums[blockIdx.x] = s[t];
}

__global__ __launch_bounds__(1024) void k_scan2(int* bsums, int nb) {
    __shared__ int s[1024];
    int t = threadIdx.x;
    s[t] = (t < nb) ? bsums[t] : 0;
    __syncthreads();
    for (int off = 1; off < 1024; off <<= 1) {
        int add = (t >= off) ? s[t - off] : 0;
        __syncthreads();
        s[t] += add;
        __syncthreads();
    }
    if (t < nb) bsums[t] = s[t];
}

__global__ __launch_bounds__(256) void k_scan3(const int* __restrict__ partial, const int* __restrict__ bsums,
                                               int* __restrict__ rowptr, int N) {
    int idx = blockIdx.x * 256 + threadIdx.x;
    if (idx < N) {
        int off = blockIdx.x > 0 ? bsums[blockIdx.x - 1] : 0;
        rowptr[idx + 1] = partial[idx] + off;
        if (idx == 0) rowptr[0] = 0;
    }
}

__global__ __launch_bounds__(256) void k_finish_deg_i(const int* __restrict__ cnt,
                                                      float* __restrict__ dinv,
                                                      float* __restrict__ selfw, int N) {
    int i = blockIdx.x * 256 + threadIdx.x;
    if (i < N) {
        float d = 1.0f + (float)cnt[i];
        dinv[i] = rsqrtf(d);
        selfw[i] = 1.0f / d;
    }
}

__global__ __launch_bounds__(256) void k_scatter(const int* __restrict__ src, const int* __restrict__ dst,
                                                 const float* __restrict__ dinv, const int* __restrict__ rowptr,
                                                 int* __restrict__ fill, int* __restrict__ esrc,
                                                 float* __restrict__ ewt, int E) {
    int e = blockIdx.x * 256 + threadIdx.x;
    if (e >= E) return;
    int s = src[e], d = dst[e];
    int pos = rowptr[d] + atomicAdd(&fill[d], 1);
    esrc[pos] = s;
    ewt[pos] = dinv[s] * dinv[d];
}

// ---------------- conversions ----------------
__global__ __launch_bounds__(256) void k_cvt(const float* __restrict__ in, ushort* __restrict__ out, long n) {
    long i = (long)blockIdx.x * 256 + threadIdx.x;
    if (i < n) out[i] = f2bf(in[i]);
}

// Wt[m][k] = bf16(W[k][m]); W is K x M row-major
__global__ __launch_bounds__(256) void k_tcvt(const float* __restrict__ W, ushort* __restrict__ Wt,
                                              int K, int M) {
    int idx = blockIdx.x * 256 + threadIdx.x;
    if (idx >= K * M) return;
    int k = idx / M, m = idx - k * M;
    Wt[(size_t)m * K + k] = f2bf(W[idx]);
}

// ---------------- CSR gather (bf16 in, fp32 acc, bf16 out) ----------------
__global__ __launch_bounds__(256) void k_gather_b4(const ushort* __restrict__ xin, const int* __restrict__ rowptr,
                                                   const int* __restrict__ esrc, const float* __restrict__ ewt,
                                                   const float* __restrict__ selfw, ushort* __restrict__ p,
                                                   int N, int SX, int SP) {
    int node = blockIdx.x * 4 + (threadIdx.x >> 6);
    if (node >= N) return;
    int c = (threadIdx.x & 63) << 2;
    ushort4 h = *(const ushort4*)(xin + (size_t)node * SX + c);
    float sw = selfw[node];
    float a0 = b2f(h.x) * sw, a1 = b2f(h.y) * sw, a2 = b2f(h.z) * sw, a3 = b2f(h.w) * sw;
    int j = rowptr[node], r1 = rowptr[node + 1];
    for (; j + 1 < r1; j += 2) {
        int s0 = esrc[j], s1 = esrc[j + 1];
        float w0 = ewt[j], w1 = ewt[j + 1];
        ushort4 v0 = *(const ushort4*)(xin + (size_t)s0 * SX + c);
        ushort4 v1 = *(const ushort4*)(xin + (size_t)s1 * SX + c);
        a0 += b2f(v0.x) * w0 + b2f(v1.x) * w1;
        a1 += b2f(v0.y) * w0 + b2f(v1.y) * w1;
        a2 += b2f(v0.z) * w0 + b2f(v1.z) * w1;
        a3 += b2f(v0.w) * w0 + b2f(v1.w) * w1;
    }
    if (j < r1) {
        int s0 = esrc[j];
        float w0 = ewt[j];
        ushort4 v0 = *(const ushort4*)(xin + (size_t)s0 * SX + c);
        a0 += b2f(v0.x) * w0; a1 += b2f(v0.y) * w0; a2 += b2f(v0.z) * w0; a3 += b2f(v0.w) * w0;
    }
    ushort4 o;
    o.x = f2bf(a0); o.y = f2bf(a1); o.z = f2bf(a2); o.w = f2bf(a3);
    *(ushort4*)(p + (size_t)node * SP + c) = o;
}

__global__ __launch_bounds__(256) void k_gather_b2(const ushort* __restrict__ xin, const int* __restrict__ rowptr,
                                                   const int* __restrict__ esrc, const float* __restrict__ ewt,
                                                   const float* __restrict__ selfw, ushort* __restrict__ p,
                                                   int N, int SX, int SP) {
    int node = blockIdx.x * 4 + (threadIdx.x >> 6);
    if (node >= N) return;
    int c = (threadIdx.x & 63) << 1;
    ushort2 h = *(const ushort2*)(xin + (size_t)node * SX + c);
    float sw = selfw[node];
    float a0 = b2f(h.x) * sw, a1 = b2f(h.y) * sw;
    int j = rowptr[node], r1 = rowptr[node + 1];
    for (; j + 1 < r1; j += 2) {
        int s0 = esrc[j], s1 = esrc[j + 1];
        float w0 = ewt[j], w1 = ewt[j + 1];
        ushort2 v0 = *(const ushort2*)(xin + (size_t)s0 * SX + c);
        ushort2 v1 = *(const ushort2*)(xin + (size_t)s1 * SX + c);
        a0 += b2f(v0.x) * w0 + b2f(v1.x) * w1;
        a1 += b2f(v0.y) * w0 + b2f(v1.y) * w1;
    }
    if (j < r1) {
        int s0 = esrc[j];
        float w0 = ewt[j];
        ushort2 v0 = *(const ushort2*)(xin + (size_t)s0 * SX + c);
        a0 += b2f(v0.x) * w0; a1 += b2f(v0.y) * w0;
    }
    ushort2 o;
    o.x = f2bf(a0); o.y = f2bf(a1);
    *(ushort2*)(p + (size_t)node * SP + c) = o;
}

// ---------------- fused dual-GEMM MFMA:  Out = relu(Pm@Wc + bc) + X@Wd + bd ----------------
__global__ __launch_bounds__(256, 2) void k_fused_mfma(
    const ushort* __restrict__ Pm, const ushort* __restrict__ X,
    const ushort* __restrict__ Wct, const ushort* __restrict__ Wdt,
    const float* __restrict__ bc, const float* __restrict__ bd,
    ushort* __restrict__ Out, int N, int K, int SP, int SX) {
    __shared__ short Ps[64 * LDK];
    __shared__ short Xs[64 * LDK];
    __shared__ short Wcs[256 * LDK];
    __shared__ short Wds[256 * LDK];
    const int tid = threadIdx.x;
    const int wave = tid >> 6, lane = tid & 63;
    const int row0 = blockIdx.x * 64;

    f32x4 accC[4][4], accD[4][4];
#pragma unroll
    for (int i = 0; i < 4; ++i)
#pragma unroll
        for (int j = 0; j < 4; ++j) { accC[i][j] = (f32x4)0.f; accD[i][j] = (f32x4)0.f; }

    const int sr = tid >> 2, sc = (tid & 3) * 8;
    int grow = row0 + sr; if (grow > N - 1) grow = N - 1;
    const int m = lane & 15, kh = (lane >> 4) * 8;

    for (int k0 = 0; k0 < K; k0 += 32) {
        *(uint4*)&Ps[sr * LDK + sc] = *(const uint4*)(Pm + (size_t)grow * SP + k0 + sc);
        *(uint4*)&Xs[sr * LDK + sc] = *(const uint4*)(X + (size_t)grow * SX + k0 + sc);
#pragma unroll
        for (int p = 0; p < 4; ++p) {
            int col = p * 64 + (tid >> 2);
            *(uint4*)&Wcs[col * LDK + sc] = *(const uint4*)(Wct + (size_t)col * K + k0 + sc);
            *(uint4*)&Wds[col * LDK + sc] = *(const uint4*)(Wdt + (size_t)col * K + k0 + sc);
        }
        __syncthreads();
        bf16x8 aP[4], aX[4], bC[4], bD[4];
#pragma unroll
        for (int i = 0; i < 4; ++i) {
            aP[i] = *(bf16x8*)&Ps[(16 * i + m) * LDK + kh];
            aX[i] = *(bf16x8*)&Xs[(16 * i + m) * LDK + kh];
        }
#pragma unroll
        for (int j = 0; j < 4; ++j) {
            int c = wave * 64 + 16 * j + m;
            bC[j] = *(bf16x8*)&Wcs[c * LDK + kh];
            bD[j] = *(bf16x8*)&Wds[c * LDK + kh];
        }
#pragma unroll
        for (int i = 0; i < 4; ++i)
#pragma unroll
            for (int j = 0; j < 4; ++j) {
                accC[i][j] = __builtin_amdgcn_mfma_f32_16x16x32_bf16(aP[i], bC[j], accC[i][j], 0, 0, 0);
                accD[i][j] = __builtin_amdgcn_mfma_f32_16x16x32_bf16(aX[i], bD[j], accD[i][j], 0, 0, 0);
            }
        __syncthreads();
    }

    const int rq = (lane >> 4) * 4;
#pragma unroll
    for (int j = 0; j < 4; ++j) {
        int col = wave * 64 + 16 * j + m;
        float bcv = bc[col], bdv = bd[col];
#pragma unroll
        for (int i = 0; i < 4; ++i)
#pragma unroll
            for (int g = 0; g < 4; ++g) {
                int row = row0 + 16 * i + rq + g;
                if (row < N) {
                    float v = fmaxf(accC[i][j][g] + bcv, 0.f) + accD[i][j][g] + bdv;
                    Out[(size_t)row * 256 + col] = f2bf(v);
                }
            }
    }
}

// ---------------- single-GEMM MFMA:  Out = [relu](A@W + b) ----------------
__global__ __launch_bounds__(256, 2) void k_gemm_mfma(
    const ushort* __restrict__ A, const ushort* __restrict__ Wt, const float* __restrict__ bias,
    ushort* __restrict__ Out, int N, int K, int M, int SA, int dorelu) {
    __shared__ short As[128 * LDK];
    __shared__ short Wls[256 * LDK];
    const int tid = threadIdx.x;
    const int wave = tid >> 6, lane = tid & 63;
    const int MW = M >> 6;          // 2 or 4
    const int R = 16384 / M;        // 128 or 64
    const int row0 = blockIdx.x * R;
    const int row_off = (wave / MW) * 64, col_off = (wave % MW) * 64;

    f32x4 acc[4][4];
#pragma unroll
    for (int i = 0; i < 4; ++i)
#pragma unroll
        for (int j = 0; j < 4; ++j) acc[i][j] = (f32x4)0.f;

    const int m = lane & 15, kh = (lane >> 4) * 8, sc = (tid & 3) * 8;

    for (int k0 = 0; k0 < K; k0 += 32) {
        for (int c = tid; c < R * 4; c += 256) {
            int r = c >> 2, ck = (c & 3) * 8;
            int gr = row0 + r; if (gr > N - 1) gr = N - 1;
            *(uint4*)&As[r * LDK + ck] = *(const uint4*)(A + (size_t)gr * SA + k0 + ck);
        }
        for (int p = 0; p < MW; ++p) {
            int col = p * 64 + (tid >> 2);
            *(uint4*)&Wls[col * LDK + sc] = *(const uint4*)(Wt + (size_t)col * K + k0 + sc);
        }
        __syncthreads();
        bf16x8 af[4], bf[4];
#pragma unroll
        for (int i = 0; i < 4; ++i) af[i] = *(bf16x8*)&As[(row_off + 16 * i + m) * LDK + kh];
#pragma unroll
        for (int j = 0; j < 4; ++j) bf[j] = *(bf16x8*)&Wls[(col_off + 16 * j + m) * LDK + kh];
#pragma unroll
        for (int i = 0; i < 4; ++i)
#pragma unroll
            for (int j = 0; j < 4; ++j)
                acc[i][j] = __builtin_amdgcn_mfma_f32_16x16x32_bf16(af[i], bf[j], acc[i][j], 0, 0, 0);
        __syncthreads();
    }

    const int rq = (lane >> 4) * 4;
#pragma unroll
    for (int j = 0; j < 4; ++j) {
        int col = col_off + 16 * j + m;
        float bv = bias[col];
#pragma unroll
        for (int i = 0; i < 4; ++i)
#pragma unroll
            for (int g = 0; g < 4; ++g) {
                int row = row0 + row_off + 16 * i + rq + g;
                if (row < N) {
                    float v = acc[i][j][g] + bv;
                    if (dorelu) v = fmaxf(v, 0.f);
                    Out[(size_t)row * M + col] = f2bf(v);
                }
            }
    }
}

// ---------------- pooling ----------------
__global__ void k_ranges(const int* __restrict__ batch, int N, int B, int* __restrict__ start,
                         float* __restrict__ countsf) {
    int b = threadIdx.x;
    if (b <= B) {
        int lo = 0, hi = N;
        while (lo < hi) {
            int mid = (lo + hi) >> 1;
            if (batch[mid] < b) lo = mid + 1; else hi = mid;
        }
        start[b] = lo;
    }
    __syncthreads();
    if (b < B) {
        int cnt = start[b + 1] - start[b];
        countsf[b] = (float)(cnt > 0 ? cnt : 1);
    }
}

__global__ __launch_bounds__(256) void k_pool1b(const ushort* __restrict__ M_, const int* __restrict__ start,
                                                const float* __restrict__ countsf, float* __restrict__ out) {
    int b = blockIdx.x >> 2;
    int chunk = blockIdx.x & 3;
    int col = chunk * 64 + (threadIdx.x & 63);
    int stripe = threadIdx.x >> 6;
    int r0 = start[b], r1 = start[b + 1];
    float s = 0.f;
    for (int r = r0 + stripe; r < r1; r += 4) s += b2f(M_[(size_t)r * 256 + col]);
    __shared__ float red[4][64];
    red[stripe][threadIdx.x & 63] = s;
    __syncthreads();
    if (stripe == 0) {
        int c = threadIdx.x & 63;
        float v = (red[0][c] + red[1][c] + red[2][c] + red[3][c]) / countsf[b];
        out[(size_t)b * 256 + col] = v;
    }
}

// ---------------- fused per-graph head (fp32): one block per graph ----------------
// LDS-staged row vectors; thread-per-col dense layers with unroll-8 K loops;
// wave-per-output shuffle reduce for tiny-M heads.
__device__ __forceinline__ void dense_tc(const float* __restrict__ vin, const float* __restrict__ W,
                                         const float* __restrict__ bias, float* __restrict__ vout,
                                         int K, int M, int relu, int tid) {
    for (int c = tid; c < M; c += 256) {
        float s = bias[c];
#pragma unroll 8
        for (int k = 0; k < K; ++k) s += vin[k] * W[(size_t)k * M + c];
        if (relu) s = fmaxf(s, 0.f);
        vout[c] = s;
    }
}

__global__ __launch_bounds__(256) void k_head(
    const float* __restrict__ sf, const float* __restrict__ tf,
    const int* __restrict__ tidx, const float* __restrict__ temb,
    const float* __restrict__ ge, const float* __restrict__ pe,
    const float* __restrict__ Ws1, const float* __restrict__ bs1,
    const float* __restrict__ Ws2, const float* __restrict__ bs2,
    const float* __restrict__ Wt1, const float* __restrict__ bt1,
    const float* __restrict__ Wt2, const float* __restrict__ bt2,
    const float* __restrict__ Wf1, const float* __restrict__ bf1,
    const float* __restrict__ Wf2, const float* __restrict__ bf2,
    const float* __restrict__ Wg, const float* __restrict__ bg,
    const float* __restrict__ Wtp, const float* __restrict__ btp,
    float* __restrict__ out_fused, float* __restrict__ out_logits, float* __restrict__ out_tp,
    int DS, int NG) {
    __shared__ float lsf[1024];
    __shared__ float ls1[256];
    __shared__ float lt1[128];
    __shared__ float lcomb[1280];
    __shared__ float lfh[512];
    __shared__ float lfused[256];
    __shared__ float ltf[8];

    const int b = blockIdx.x;
    const int tid = threadIdx.x;
    const int wave = tid >> 6, lane = tid & 63;

    // stage inputs
    for (int i = tid; i < DS; i += 256) lsf[i] = sf[(size_t)b * DS + i];
    if (tid < 5) ltf[tid] = tf[(size_t)b * 5 + tid];
    lcomb[tid] = ge[(size_t)b * 256 + tid];
    lcomb[1024 + tid] = pe[(size_t)b * 256 + tid];
    lcomb[768 + tid] = temb[(size_t)tidx[b] * 256 + tid];
    __syncthreads();

    // static encoder: s1 = relu(sf@Ws1+bs1); se = s1@Ws2+bs2 -> comb[256..511]
    dense_tc(lsf, Ws1, bs1, ls1, DS, 256, 1, tid);
    __syncthreads();
    dense_tc(ls1, Ws2, bs2, &lcomb[256], 256, 256, 0, tid);
    // temporal: t1 = relu(tf@Wt1+bt1); te = t1@Wt2+bt2 -> comb[512..767]
    dense_tc(ltf, Wt1, bt1, lt1, 5, 128, 1, tid);
    __syncthreads();
    dense_tc(lt1, Wt2, bt2, &lcomb[512], 128, 256, 0, tid);
    __syncthreads();

    // fusion: fh = relu(comb@Wf1+bf1); fused = fh@Wf2+bf2
    dense_tc(lcomb, Wf1, bf1, lfh, 1280, 512, 1, tid);
    __syncthreads();
    dense_tc(lfh, Wf2, bf2, lfused, 512, 256, 0, tid);
    __syncthreads();

    out_fused[(size_t)b * 256 + tid] = lfused[tid];

    // group logits: wave w handles cols w, w+4, ... (K=256, lane-split + butterfly)
    for (int c = wave; c < NG; c += 4) {
        float s = 0.f;
#pragma unroll
        for (int k = lane; k < 256; k += 64) s += lfused[k] * Wg[(size_t)k * NG + c];
#pragma unroll
        for (int off = 32; off > 0; off >>= 1) s += __shfl_down(s, off, 64);
        if (lane == 0) out_logits[(size_t)b * NG + c] = s + bg[c];
    }
    // time pred (wave 0)
    if (wave == 0) {
        float s = 0.f;
#pragma unroll
        for (int k = lane; k < 256; k += 64) s += lfused[k] * Wtp[k];
#pragma unroll
        for (int off = 32; off > 0; off >>= 1) s += __shfl_down(s, off, 64);
        if (lane == 0) out_tp[b] = s + btp[0];
    }
}

// ---------------- host launch ----------------
extern "C" void kernel_launch(void* const* d_in, const int* in_sizes, int n_in,
                              void* d_out, int out_size, void* d_ws, size_t ws_size,
                              hipStream_t stream) {
    const float* x   = (const float*)d_in[0];
    const int* ei    = (const int*)d_in[1];
    const int* batch = (const int*)d_in[2];
    const float* sf  = (const float*)d_in[3];
    const float* tf  = (const float*)d_in[4];
    const int* tidx  = (const int*)d_in[5];
    const float* temb = (const float*)d_in[6];
    const float *Ws1 = (const float*)d_in[7],  *bs1 = (const float*)d_in[8];
    const float *Ws2 = (const float*)d_in[9],  *bs2 = (const float*)d_in[10];
    const float *Wc1 = (const float*)d_in[11], *bc1 = (const float*)d_in[12];
    const float *Wc2 = (const float*)d_in[13], *bc2 = (const float*)d_in[14];
    const float *Wc3 = (const float*)d_in[15], *bc3 = (const float*)d_in[16];
    const float *Wd1 = (const float*)d_in[17], *bd1 = (const float*)d_in[18];
    const float *Wd2 = (const float*)d_in[19], *bd2 = (const float*)d_in[20];
    const float *Wd3 = (const float*)d_in[21], *bd3 = (const float*)d_in[22];
    const float *Wt1 = (const float*)d_in[23], *bt1 = (const float*)d_in[24];
    const float *Wt2 = (const float*)d_in[25], *bt2 = (const float*)d_in[26];
    const float *Wp1 = (const float*)d_in[27], *bp1 = (const float*)d_in[28];
    const float *Wp2 = (const float*)d_in[29], *bp2 = (const float*)d_in[30];
    const float *Wf1 = (const float*)d_in[31], *bf1 = (const float*)d_in[32];
    const float *Wf2 = (const float*)d_in[33], *bf2 = (const float*)d_in[34];
    const float *Wg  = (const float*)d_in[35], *bg  = (const float*)d_in[36];
    const float *Wtp = (const float*)d_in[37], *btp = (const float*)d_in[38];

    const int N = in_sizes[2];
    const int E = in_sizes[1] / 2;
    const int B = in_sizes[5];
    const int DS = in_sizes[3] / B;        // 1024
    const int NG = in_sizes[36];           // 20
    const int* src = ei;
    const int* dst = ei + E;

    // ---- workspace layout ----
    char* w = (char*)d_ws;
    ushort* A   = (ushort*)w;              w += (size_t)N * 256 * 2;
    ushort* Bb  = (ushort*)w;              w += (size_t)N * 256 * 2;
    ushort* xh  = (ushort*)w;              w += (size_t)N * 128 * 2;
    ushort* Wc1t = (ushort*)w;             w += 128 * 256 * 2;
    ushort* Wd1t = (ushort*)w;             w += 128 * 256 * 2;
    ushort* Wc2t = (ushort*)w;             w += 256 * 256 * 2;
    ushort* Wd2t = (ushort*)w;             w += 256 * 256 * 2;
    ushort* Wc3t = (ushort*)w;             w += 256 * 256 * 2;
    ushort* Wd3t = (ushort*)w;             w += 256 * 256 * 2;
    ushort* Wp1t = (ushort*)w;             w += 256 * 128 * 2;
    ushort* Wp2t = (ushort*)w;             w += 128 * 256 * 2;
    int* esrc   = (int*)w;                 w += (size_t)E * 4;
    float* ewt  = (float*)w;               w += (size_t)E * 4;
    int* cnt    = (int*)w;                 w += (size_t)N * 4;
    int* part   = (int*)w;                 w += (size_t)N * 4;
    int* rowptr = (int*)w;                 w += (size_t)(N + 1) * 4;
    int* fill   = (int*)w;                 w += (size_t)N * 4;
    int* bsums  = (int*)w;                 w += 1024 * 4;
    float* dinv = (float*)w;               w += (size_t)N * 4;
    float* selfw = (float*)w;              w += (size_t)N * 4;
    int* startp = (int*)w;                 w += (B + 1) * 4;
    float* countsf = (float*)w;            w += B * 4;
    float* ge = (float*)w;                 w += B * 256 * 4;
    float* pe = (float*)w;                 w += B * 256 * 4;

    float* out_fused = (float*)d_out;                 // B x 256
    float* out_logits = out_fused + (size_t)B * H;    // B x NG
    float* out_tp = out_logits + (size_t)B * NG;      // B x 1

    dim3 blk(256);
    const int nbN = (N + 255) / 256;
    const int nbE = (E + 255) / 256;

    // ---- CSR build ----
    k_zero_i<<<dim3(nbN), blk, 0, stream>>>(cnt, N);
    k_zero_i<<<dim3(nbN), blk, 0, stream>>>(fill, N);
    k_count_deg_i<<<dim3(nbE), blk, 0, stream>>>(dst, cnt, E);
    k_scan1<<<dim3(nbN), blk, 0, stream>>>(cnt, part, bsums, N);
    k_scan2<<<dim3(1), dim3(1024), 0, stream>>>(bsums, nbN);
    k_scan3<<<dim3(nbN), blk, 0, stream>>>(part, bsums, rowptr, N);
    k_finish_deg_i<<<dim3(nbN), blk, 0, stream>>>(cnt, dinv, selfw, N);
    k_scatter<<<dim3(nbE), blk, 0, stream>>>(src, dst, dinv, rowptr, fill, esrc, ewt, E);

    // ---- conversions ----
    {
        long nx = (long)N * 128;
        k_cvt<<<dim3((unsigned)((nx + 255) / 256)), blk, 0, stream>>>(x, xh, nx);
        k_tcvt<<<dim3((128 * 256 + 255) / 256), blk, 0, stream>>>(Wc1, Wc1t, 128, 256);
        k_tcvt<<<dim3((128 * 256 + 255) / 256), blk, 0, stream>>>(Wd1, Wd1t, 128, 256);
        k_tcvt<<<dim3((256 * 256 + 255) / 256), blk, 0, stream>>>(Wc2, Wc2t, 256, 256);
        k_tcvt<<<dim3((256 * 256 + 255) / 256), blk, 0, stream>>>(Wd2, Wd2t, 256, 256);
        k_tcvt<<<dim3((256 * 256 + 255) / 256), blk, 0, stream>>>(Wc3, Wc3t, 256, 256);
        k_tcvt<<<dim3((256 * 256 + 255) / 256), blk, 0, stream>>>(Wd3, Wd3t, 256, 256);
        k_tcvt<<<dim3((256 * 128 + 255) / 256), blk, 0, stream>>>(Wp1, Wp1t, 256, 128);
        k_tcvt<<<dim3((128 * 256 + 255) / 256), blk, 0, stream>>>(Wp2, Wp2t, 128, 256);
    }

    const int ngb = (N + 3) / 4;
    const int nfb = (N + 63) / 64;

    // ---- 3 GCN layers ----
    k_gather_b2<<<dim3(ngb), blk, 0, stream>>>(xh, rowptr, esrc, ewt, selfw, A, N, 128, 128);
    k_fused_mfma<<<dim3(nfb), blk, 0, stream>>>(A, xh, Wc1t, Wd1t, bc1, bd1, Bb, N, 128, 128, 128);
    k_gather_b4<<<dim3(ngb), blk, 0, stream>>>(Bb, rowptr, esrc, ewt, selfw, A, N, 256, 256);
    k_fused_mfma<<<dim3(nfb), blk, 0, stream>>>(A, Bb, Wc2t, Wd2t, bc2, bd2, A, N, 256, 256, 256);
    k_gather_b4<<<dim3(ngb), blk, 0, stream>>>(A, rowptr, esrc, ewt, selfw, Bb, N, 256, 256);
    k_fused_mfma<<<dim3(nfb), blk, 0, stream>>>(Bb, A, Wc3t, Wd3t, bc3, bd3, Bb, N, 256, 256, 256);

    // ---- pooling ranges + ge from x3 (Bb) ----
    k_ranges<<<dim3(1), dim3(128), 0, stream>>>(batch, N, B, startp, countsf);
    k_pool1b<<<dim3(B * 4), blk, 0, stream>>>(Bb, startp, countsf, ge);

    // ---- pattern detector + pe ----
    k_gemm_mfma<<<dim3((N + 127) / 128), blk, 0, stream>>>(Bb, Wp1t, bp1, A, N, 256, 128, 256, 1);
    k_gemm_mfma<<<dim3((N + 63) / 64), blk, 0, stream>>>(A, Wp2t, bp2, Bb, N, 128, 256, 128, 1);
    k_pool1b<<<dim3(B * 4), blk, 0, stream>>>(Bb, startp, countsf, pe);

    // ---- fused per-graph head (fp32) ----
    k_head<<<dim3(B), blk, 0, stream>>>(sf, tf, tidx, temb, ge, pe,
                                        Ws1, bs1, Ws2, bs2, Wt1, bt1, Wt2, bt2,
                                        Wf1, bf1, Wf2, bf2, Wg, bg, Wtp, btp,
                                        out_fused, out_logits, out_tp, DS, NG);
}

// Round 6
// 1119.038 us; speedup vs baseline: 10.2167x; 1.1519x over previous
//
#include <hip/hip_runtime.h>

#define H 256
#define LDK 40  // padded k-stride (halves): 80B rows -> <=2-way LDS bank aliasing (free)

typedef __attribute__((ext_vector_type(8))) short bf16x8;
typedef __attribute__((ext_vector_type(4))) float f32x4;

__device__ __forceinline__ float b2f(ushort h) {
    return __uint_as_float(((unsigned)h) << 16);
}
__device__ __forceinline__ ushort f2bf(float f) {
    unsigned u = __float_as_uint(f);
    unsigned r = (u + 0x7FFF + ((u >> 16) & 1)) >> 16;  // RNE
    return (ushort)r;
}

// ---------------- CSR build ----------------
__global__ __launch_bounds__(256) void k_zero_i(int* p, int n) {
    int i = blockIdx.x * 256 + threadIdx.x;
    if (i < n) p[i] = 0;
}

__global__ __launch_bounds__(256) void k_count_deg_i(const int* __restrict__ dst, int* cnt, int E) {
    int i = blockIdx.x * 256 + threadIdx.x;
    if (i < E) atomicAdd(&cnt[dst[i]], 1);
}

__global__ __launch_bounds__(256) void k_scan1(const int* __restrict__ cnt, int* __restrict__ partial,
                                               int* __restrict__ bsums, int N) {
    __shared__ int s[256];
    int t = threadIdx.x;
    int idx = blockIdx.x * 256 + t;
    int v = idx < N ? cnt[idx] : 0;
    s[t] = v;
    __syncthreads();
    for (int off = 1; off < 256; off <<= 1) {
        int add = (t >= off) ? s[t - off] : 0;
        __syncthreads();
        s[t] += add;
        __syncthreads();
    }
    if (idx < N) partial[idx] = s[t];
    if (t == 255) bsums[blockIdx.x] = s[t];
}

__global__ __launch_bounds__(1024) void k_scan2(int* bsums, int nb) {
    __shared__ int s[1024];
    int t = threadIdx.x;
    s[t] = (t < nb) ? bsums[t] : 0;
    __syncthreads();
    for (int off = 1; off < 1024; off <<= 1) {
        int add = (t >= off) ? s[t - off] : 0;
        __syncthreads();
        s[t] += add;
        __syncthreads();
    }
    if (t < nb) bsums[t] = s[t];
}

__global__ __launch_bounds__(256) void k_scan3(const int* __restrict__ partial, const int* __restrict__ bsums,
                                               int* __restrict__ rowptr, int N) {
    int idx = blockIdx.x * 256 + threadIdx.x;
    if (idx < N) {
        int off = blockIdx.x > 0 ? bsums[blockIdx.x - 1] : 0;
        rowptr[idx + 1] = partial[idx] + off;
        if (idx == 0) rowptr[0] = 0;
    }
}

__global__ __launch_bounds__(256) void k_finish_deg_i(const int* __restrict__ cnt,
                                                      float* __restrict__ dinv,
                                                      float* __restrict__ selfw, int N) {
    int i = blockIdx.x * 256 + threadIdx.x;
    if (i < N) {
        float d = 1.0f + (float)cnt[i];
        dinv[i] = rsqrtf(d);
        selfw[i] = 1.0f / d;
    }
}

__global__ __launch_bounds__(256) void k_scatter(const int* __restrict__ src, const int* __restrict__ dst,
                                                 const float* __restrict__ dinv, const int* __restrict__ rowptr,
                                                 int* __restrict__ fill, int* __restrict__ esrc,
                                                 float* __restrict__ ewt, int E) {
    int e = blockIdx.x * 256 + threadIdx.x;
    if (e >= E) return;
    int s = src[e], d = dst[e];
    int pos = rowptr[d] + atomicAdd(&fill[d], 1);
    esrc[pos] = s;
    ewt[pos] = dinv[s] * dinv[d];
}

// ---------------- conversions ----------------
__global__ __launch_bounds__(256) void k_cvt(const float* __restrict__ in, ushort* __restrict__ out, long n) {
    long i = (long)blockIdx.x * 256 + threadIdx.x;
    if (i < n) out[i] = f2bf(in[i]);
}

__global__ __launch_bounds__(256) void k_tcvt(const float* __restrict__ W, ushort* __restrict__ Wt,
                                              int K, int M) {
    int idx = blockIdx.x * 256 + threadIdx.x;
    if (idx >= K * M) return;
    int k = idx / M, m = idx - k * M;
    Wt[(size_t)m * K + k] = f2bf(W[idx]);
}

// ---------------- CSR gather (bf16 in, fp32 acc, bf16 out) ----------------
__global__ __launch_bounds__(256) void k_gather_b4(const ushort* __restrict__ xin, const int* __restrict__ rowptr,
                                                   const int* __restrict__ esrc, const float* __restrict__ ewt,
                                                   const float* __restrict__ selfw, ushort* __restrict__ p,
                                                   int N, int SX, int SP) {
    int node = blockIdx.x * 4 + (threadIdx.x >> 6);
    if (node >= N) return;
    int c = (threadIdx.x & 63) << 2;
    ushort4 h = *(const ushort4*)(xin + (size_t)node * SX + c);
    float sw = selfw[node];
    float a0 = b2f(h.x) * sw, a1 = b2f(h.y) * sw, a2 = b2f(h.z) * sw, a3 = b2f(h.w) * sw;
    int j = rowptr[node], r1 = rowptr[node + 1];
    for (; j + 3 < r1; j += 4) {
        int s0 = esrc[j], s1 = esrc[j + 1], s2 = esrc[j + 2], s3 = esrc[j + 3];
        float w0 = ewt[j], w1 = ewt[j + 1], w2 = ewt[j + 2], w3 = ewt[j + 3];
        ushort4 v0 = *(const ushort4*)(xin + (size_t)s0 * SX + c);
        ushort4 v1 = *(const ushort4*)(xin + (size_t)s1 * SX + c);
        ushort4 v2 = *(const ushort4*)(xin + (size_t)s2 * SX + c);
        ushort4 v3 = *(const ushort4*)(xin + (size_t)s3 * SX + c);
        a0 += b2f(v0.x) * w0 + b2f(v1.x) * w1 + b2f(v2.x) * w2 + b2f(v3.x) * w3;
        a1 += b2f(v0.y) * w0 + b2f(v1.y) * w1 + b2f(v2.y) * w2 + b2f(v3.y) * w3;
        a2 += b2f(v0.z) * w0 + b2f(v1.z) * w1 + b2f(v2.z) * w2 + b2f(v3.z) * w3;
        a3 += b2f(v0.w) * w0 + b2f(v1.w) * w1 + b2f(v2.w) * w2 + b2f(v3.w) * w3;
    }
    for (; j < r1; ++j) {
        int s0 = esrc[j];
        float w0 = ewt[j];
        ushort4 v0 = *(const ushort4*)(xin + (size_t)s0 * SX + c);
        a0 += b2f(v0.x) * w0; a1 += b2f(v0.y) * w0; a2 += b2f(v0.z) * w0; a3 += b2f(v0.w) * w0;
    }
    ushort4 o;
    o.x = f2bf(a0); o.y = f2bf(a1); o.z = f2bf(a2); o.w = f2bf(a3);
    *(ushort4*)(p + (size_t)node * SP + c) = o;
}

__global__ __launch_bounds__(256) void k_gather_b2(const ushort* __restrict__ xin, const int* __restrict__ rowptr,
                                                   const int* __restrict__ esrc, const float* __restrict__ ewt,
                                                   const float* __restrict__ selfw, ushort* __restrict__ p,
                                                   int N, int SX, int SP) {
    int node = blockIdx.x * 4 + (threadIdx.x >> 6);
    if (node >= N) return;
    int c = (threadIdx.x & 63) << 1;
    ushort2 h = *(const ushort2*)(xin + (size_t)node * SX + c);
    float sw = selfw[node];
    float a0 = b2f(h.x) * sw, a1 = b2f(h.y) * sw;
    int j = rowptr[node], r1 = rowptr[node + 1];
    for (; j + 3 < r1; j += 4) {
        int s0 = esrc[j], s1 = esrc[j + 1], s2 = esrc[j + 2], s3 = esrc[j + 3];
        float w0 = ewt[j], w1 = ewt[j + 1], w2 = ewt[j + 2], w3 = ewt[j + 3];
        ushort2 v0 = *(const ushort2*)(xin + (size_t)s0 * SX + c);
        ushort2 v1 = *(const ushort2*)(xin + (size_t)s1 * SX + c);
        ushort2 v2 = *(const ushort2*)(xin + (size_t)s2 * SX + c);
        ushort2 v3 = *(const ushort2*)(xin + (size_t)s3 * SX + c);
        a0 += b2f(v0.x) * w0 + b2f(v1.x) * w1 + b2f(v2.x) * w2 + b2f(v3.x) * w3;
        a1 += b2f(v0.y) * w0 + b2f(v1.y) * w1 + b2f(v2.y) * w2 + b2f(v3.y) * w3;
    }
    for (; j < r1; ++j) {
        int s0 = esrc[j];
        float w0 = ewt[j];
        ushort2 v0 = *(const ushort2*)(xin + (size_t)s0 * SX + c);
        a0 += b2f(v0.x) * w0; a1 += b2f(v0.y) * w0;
    }
    ushort2 o;
    o.x = f2bf(a0); o.y = f2bf(a1);
    *(ushort2*)(p + (size_t)node * SP + c) = o;
}

// ---------------- fused dual-GEMM MFMA:  Out = relu(Pm@Wc + bc) + X@Wd + bd ----------------
__global__ __launch_bounds__(256, 2) void k_fused_mfma(
    const ushort* __restrict__ Pm, const ushort* __restrict__ X,
    const ushort* __restrict__ Wct, const ushort* __restrict__ Wdt,
    const float* __restrict__ bc, const float* __restrict__ bd,
    ushort* __restrict__ Out, int N, int K, int SP, int SX) {
    __shared__ short Ps[64 * LDK];
    __shared__ short Xs[64 * LDK];
    __shared__ short Wcs[256 * LDK];
    __shared__ short Wds[256 * LDK];
    const int tid = threadIdx.x;
    const int wave = tid >> 6, lane = tid & 63;
    const int row0 = blockIdx.x * 64;

    f32x4 accC[4][4], accD[4][4];
#pragma unroll
    for (int i = 0; i < 4; ++i)
#pragma unroll
        for (int j = 0; j < 4; ++j) { accC[i][j] = (f32x4)0.f; accD[i][j] = (f32x4)0.f; }

    const int sr = tid >> 2, sc = (tid & 3) * 8;
    int grow = row0 + sr; if (grow > N - 1) grow = N - 1;
    const int m = lane & 15, kh = (lane >> 4) * 8;

    for (int k0 = 0; k0 < K; k0 += 32) {
        *(uint4*)&Ps[sr * LDK + sc] = *(const uint4*)(Pm + (size_t)grow * SP + k0 + sc);
        *(uint4*)&Xs[sr * LDK + sc] = *(const uint4*)(X + (size_t)grow * SX + k0 + sc);
#pragma unroll
        for (int p = 0; p < 4; ++p) {
            int col = p * 64 + (tid >> 2);
            *(uint4*)&Wcs[col * LDK + sc] = *(const uint4*)(Wct + (size_t)col * K + k0 + sc);
            *(uint4*)&Wds[col * LDK + sc] = *(const uint4*)(Wdt + (size_t)col * K + k0 + sc);
        }
        __syncthreads();
        bf16x8 aP[4], aX[4], bC[4], bD[4];
#pragma unroll
        for (int i = 0; i < 4; ++i) {
            aP[i] = *(bf16x8*)&Ps[(16 * i + m) * LDK + kh];
            aX[i] = *(bf16x8*)&Xs[(16 * i + m) * LDK + kh];
        }
#pragma unroll
        for (int j = 0; j < 4; ++j) {
            int c = wave * 64 + 16 * j + m;
            bC[j] = *(bf16x8*)&Wcs[c * LDK + kh];
            bD[j] = *(bf16x8*)&Wds[c * LDK + kh];
        }
#pragma unroll
        for (int i = 0; i < 4; ++i)
#pragma unroll
            for (int j = 0; j < 4; ++j) {
                accC[i][j] = __builtin_amdgcn_mfma_f32_16x16x32_bf16(aP[i], bC[j], accC[i][j], 0, 0, 0);
                accD[i][j] = __builtin_amdgcn_mfma_f32_16x16x32_bf16(aX[i], bD[j], accD[i][j], 0, 0, 0);
            }
        __syncthreads();
    }

    const int rq = (lane >> 4) * 4;
#pragma unroll
    for (int j = 0; j < 4; ++j) {
        int col = wave * 64 + 16 * j + m;
        float bcv = bc[col], bdv = bd[col];
#pragma unroll
        for (int i = 0; i < 4; ++i)
#pragma unroll
            for (int g = 0; g < 4; ++g) {
                int row = row0 + 16 * i + rq + g;
                if (row < N) {
                    float v = fmaxf(accC[i][j][g] + bcv, 0.f) + accD[i][j][g] + bdv;
                    Out[(size_t)row * 256 + col] = f2bf(v);
                }
            }
    }
}

// ---------------- single-GEMM MFMA:  Out = [relu](A@W + b) ----------------
__global__ __launch_bounds__(256, 2) void k_gemm_mfma(
    const ushort* __restrict__ A, const ushort* __restrict__ Wt, const float* __restrict__ bias,
    ushort* __restrict__ Out, int N, int K, int M, int SA, int dorelu) {
    __shared__ short As[128 * LDK];
    __shared__ short Wls[256 * LDK];
    const int tid = threadIdx.x;
    const int wave = tid >> 6, lane = tid & 63;
    const int MW = M >> 6;
    const int R = 16384 / M;
    const int row0 = blockIdx.x * R;
    const int row_off = (wave / MW) * 64, col_off = (wave % MW) * 64;

    f32x4 acc[4][4];
#pragma unroll
    for (int i = 0; i < 4; ++i)
#pragma unroll
        for (int j = 0; j < 4; ++j) acc[i][j] = (f32x4)0.f;

    const int m = lane & 15, kh = (lane >> 4) * 8, sc = (tid & 3) * 8;

    for (int k0 = 0; k0 < K; k0 += 32) {
        for (int c = tid; c < R * 4; c += 256) {
            int r = c >> 2, ck = (c & 3) * 8;
            int gr = row0 + r; if (gr > N - 1) gr = N - 1;
            *(uint4*)&As[r * LDK + ck] = *(const uint4*)(A + (size_t)gr * SA + k0 + ck);
        }
        for (int p = 0; p < MW; ++p) {
            int col = p * 64 + (tid >> 2);
            *(uint4*)&Wls[col * LDK + sc] = *(const uint4*)(Wt + (size_t)col * K + k0 + sc);
        }
        __syncthreads();
        bf16x8 af[4], bf[4];
#pragma unroll
        for (int i = 0; i < 4; ++i) af[i] = *(bf16x8*)&As[(row_off + 16 * i + m) * LDK + kh];
#pragma unroll
        for (int j = 0; j < 4; ++j) bf[j] = *(bf16x8*)&Wls[(col_off + 16 * j + m) * LDK + kh];
#pragma unroll
        for (int i = 0; i < 4; ++i)
#pragma unroll
            for (int j = 0; j < 4; ++j)
                acc[i][j] = __builtin_amdgcn_mfma_f32_16x16x32_bf16(af[i], bf[j], acc[i][j], 0, 0, 0);
        __syncthreads();
    }

    const int rq = (lane >> 4) * 4;
#pragma unroll
    for (int j = 0; j < 4; ++j) {
        int col = col_off + 16 * j + m;
        float bv = bias[col];
#pragma unroll
        for (int i = 0; i < 4; ++i)
#pragma unroll
            for (int g = 0; g < 4; ++g) {
                int row = row0 + row_off + 16 * i + rq + g;
                if (row < N) {
                    float v = acc[i][j][g] + bv;
                    if (dorelu) v = fmaxf(v, 0.f);
                    Out[(size_t)row * M + col] = f2bf(v);
                }
            }
    }
}

// ---------------- pooling ----------------
__global__ void k_ranges(const int* __restrict__ batch, int N, int B, int* __restrict__ start,
                         float* __restrict__ countsf) {
    int b = threadIdx.x;
    if (b <= B) {
        int lo = 0, hi = N;
        while (lo < hi) {
            int mid = (lo + hi) >> 1;
            if (batch[mid] < b) lo = mid + 1; else hi = mid;
        }
        start[b] = lo;
    }
    __syncthreads();
    if (b < B) {
        int cnt = start[b + 1] - start[b];
        countsf[b] = (float)(cnt > 0 ? cnt : 1);
    }
}

__global__ __launch_bounds__(256) void k_pool1b(const ushort* __restrict__ M_, const int* __restrict__ start,
                                                const float* __restrict__ countsf, float* __restrict__ out) {
    int b = blockIdx.x >> 2;
    int chunk = blockIdx.x & 3;
    int col = chunk * 64 + (threadIdx.x & 63);
    int stripe = threadIdx.x >> 6;
    int r0 = start[b], r1 = start[b + 1];
    float s = 0.f;
    for (int r = r0 + stripe; r < r1; r += 4) s += b2f(M_[(size_t)r * 256 + col]);
    __shared__ float red[4][64];
    red[stripe][threadIdx.x & 63] = s;
    __syncthreads();
    if (stripe == 0) {
        int c = threadIdx.x & 63;
        float v = (red[0][c] + red[1][c] + red[2][c] + red[3][c]) / countsf[b];
        out[(size_t)b * 256 + col] = v;
    }
}

// ---------------- head: parallel fp32 dense layer ----------------
// out[b*os + oo + c] = [relu]( vin[b*vs .. +K] @ W[:,c] + bias[c] )
// grid (M/64, B); block 256 = 4 waves; wave = K-strided partial, LDS reduce.
__global__ __launch_bounds__(256) void k_dense(const float* __restrict__ vin, int vs,
                                               const float* __restrict__ W, const float* __restrict__ bias,
                                               float* __restrict__ out, int os, int oo,
                                               int K, int M, int relu) {
    const int b = blockIdx.y;
    const int wave = threadIdx.x >> 6, lane = threadIdx.x & 63;
    const int c = blockIdx.x * 64 + lane;
    const float* vrow = vin + (size_t)b * vs;
    float acc = 0.f;
    int k = wave;
    for (; k + 28 < K; k += 32) {
#pragma unroll
        for (int u = 0; u < 8; ++u)
            acc += vrow[k + 4 * u] * W[(size_t)(k + 4 * u) * M + c];
    }
    for (; k < K; k += 4)
        acc += vrow[k] * W[(size_t)k * M + c];
    __shared__ float red[4][64];
    red[wave][lane] = acc;
    __syncthreads();
    if (wave == 0) {
        float s = red[0][lane] + red[1][lane] + red[2][lane] + red[3][lane] + bias[c];
        if (relu) s = fmaxf(s, 0.f);
        out[(size_t)b * os + oo + c] = s;
    }
}

// fill comb parts from pooled embeds + type embedding (grid B, 256 thr)
__global__ __launch_bounds__(256) void k_comb(const float* __restrict__ ge, const float* __restrict__ pe,
                                              const float* __restrict__ temb, const int* __restrict__ tidx,
                                              float* __restrict__ comb) {
    int b = blockIdx.x, t = threadIdx.x;
    float* o = comb + (size_t)b * 1280;
    o[t] = ge[(size_t)b * 256 + t];
    o[768 + t] = temb[(size_t)tidx[b] * 256 + t];
    o[1024 + t] = pe[(size_t)b * 256 + t];
}

// tiny heads: logits (M=NG) + time_pred from fused (grid B, 256 thr)
__global__ __launch_bounds__(256) void k_heads_small(const float* __restrict__ fused,
                                                     const float* __restrict__ Wg, const float* __restrict__ bg,
                                                     const float* __restrict__ Wtp, const float* __restrict__ btp,
                                                     float* __restrict__ out_logits, float* __restrict__ out_tp,
                                                     int NG) {
    __shared__ float lf[256];
    int b = blockIdx.x, tid = threadIdx.x;
    int wave = tid >> 6, lane = tid & 63;
    lf[tid] = fused[(size_t)b * 256 + tid];
    __syncthreads();
    for (int c = wave; c < NG; c += 4) {
        float s = 0.f;
#pragma unroll
        for (int k = lane; k < 256; k += 64) s += lf[k] * Wg[(size_t)k * NG + c];
#pragma unroll
        for (int off = 32; off > 0; off >>= 1) s += __shfl_down(s, off, 64);
        if (lane == 0) out_logits[(size_t)b * NG + c] = s + bg[c];
    }
    if (wave == 0) {
        float s = 0.f;
#pragma unroll
        for (int k = lane; k < 256; k += 64) s += lf[k] * Wtp[k];
#pragma unroll
        for (int off = 32; off > 0; off >>= 1) s += __shfl_down(s, off, 64);
        if (lane == 0) out_tp[b] = s + btp[0];
    }
}

// ---------------- host launch ----------------
extern "C" void kernel_launch(void* const* d_in, const int* in_sizes, int n_in,
                              void* d_out, int out_size, void* d_ws, size_t ws_size,
                              hipStream_t stream) {
    const float* x   = (const float*)d_in[0];
    const int* ei    = (const int*)d_in[1];
    const int* batch = (const int*)d_in[2];
    const float* sf  = (const float*)d_in[3];
    const float* tf  = (const float*)d_in[4];
    const int* tidx  = (const int*)d_in[5];
    const float* temb = (const float*)d_in[6];
    const float *Ws1 = (const float*)d_in[7],  *bs1 = (const float*)d_in[8];
    const float *Ws2 = (const float*)d_in[9],  *bs2 = (const float*)d_in[10];
    const float *Wc1 = (const float*)d_in[11], *bc1 = (const float*)d_in[12];
    const float *Wc2 = (const float*)d_in[13], *bc2 = (const float*)d_in[14];
    const float *Wc3 = (const float*)d_in[15], *bc3 = (const float*)d_in[16];
    const float *Wd1 = (const float*)d_in[17], *bd1 = (const float*)d_in[18];
    const float *Wd2 = (const float*)d_in[19], *bd2 = (const float*)d_in[20];
    const float *Wd3 = (const float*)d_in[21], *bd3 = (const float*)d_in[22];
    const float *Wt1 = (const float*)d_in[23], *bt1 = (const float*)d_in[24];
    const float *Wt2 = (const float*)d_in[25], *bt2 = (const float*)d_in[26];
    const float *Wp1 = (const float*)d_in[27], *bp1 = (const float*)d_in[28];
    const float *Wp2 = (const float*)d_in[29], *bp2 = (const float*)d_in[30];
    const float *Wf1 = (const float*)d_in[31], *bf1 = (const float*)d_in[32];
    const float *Wf2 = (const float*)d_in[33], *bf2 = (const float*)d_in[34];
    const float *Wg  = (const float*)d_in[35], *bg  = (const float*)d_in[36];
    const float *Wtp = (const float*)d_in[37], *btp = (const float*)d_in[38];

    const int N = in_sizes[2];
    const int E = in_sizes[1] / 2;
    const int B = in_sizes[5];
    const int DS = in_sizes[3] / B;        // 1024
    const int NG = in_sizes[36];           // 20
    const int* src = ei;
    const int* dst = ei + E;

    // ---- workspace layout ----
    char* w = (char*)d_ws;
    ushort* A   = (ushort*)w;              w += (size_t)N * 256 * 2;
    ushort* Bb  = (ushort*)w;              w += (size_t)N * 256 * 2;
    ushort* xh  = (ushort*)w;              w += (size_t)N * 128 * 2;
    ushort* Wc1t = (ushort*)w;             w += 128 * 256 * 2;
    ushort* Wd1t = (ushort*)w;             w += 128 * 256 * 2;
    ushort* Wc2t = (ushort*)w;             w += 256 * 256 * 2;
    ushort* Wd2t = (ushort*)w;             w += 256 * 256 * 2;
    ushort* Wc3t = (ushort*)w;             w += 256 * 256 * 2;
    ushort* Wd3t = (ushort*)w;             w += 256 * 256 * 2;
    ushort* Wp1t = (ushort*)w;             w += 256 * 128 * 2;
    ushort* Wp2t = (ushort*)w;             w += 128 * 256 * 2;
    int* esrc   = (int*)w;                 w += (size_t)E * 4;
    float* ewt  = (float*)w;               w += (size_t)E * 4;
    int* cnt    = (int*)w;                 w += (size_t)N * 4;
    int* part   = (int*)w;                 w += (size_t)N * 4;
    int* rowptr = (int*)w;                 w += (size_t)(N + 1) * 4;
    int* fill   = (int*)w;                 w += (size_t)N * 4;
    int* bsums  = (int*)w;                 w += 1024 * 4;
    float* dinv = (float*)w;               w += (size_t)N * 4;
    float* selfw = (float*)w;              w += (size_t)N * 4;
    int* startp = (int*)w;                 w += (B + 1) * 4;
    float* countsf = (float*)w;            w += B * 4;
    float* ge = (float*)w;                 w += B * 256 * 4;
    float* pe = (float*)w;                 w += B * 256 * 4;
    float* s1buf = (float*)w;              w += B * 256 * 4;
    float* t1buf = (float*)w;              w += B * 128 * 4;
    float* comb = (float*)w;               w += B * 1280 * 4;
    float* fh = (float*)w;                 w += B * 512 * 4;

    float* out_fused = (float*)d_out;                 // B x 256
    float* out_logits = out_fused + (size_t)B * H;    // B x NG
    float* out_tp = out_logits + (size_t)B * NG;      // B x 1

    dim3 blk(256);
    const int nbN = (N + 255) / 256;
    const int nbE = (E + 255) / 256;

    // ---- CSR build ----
    k_zero_i<<<dim3(nbN), blk, 0, stream>>>(cnt, N);
    k_zero_i<<<dim3(nbN), blk, 0, stream>>>(fill, N);
    k_count_deg_i<<<dim3(nbE), blk, 0, stream>>>(dst, cnt, E);
    k_scan1<<<dim3(nbN), blk, 0, stream>>>(cnt, part, bsums, N);
    k_scan2<<<dim3(1), dim3(1024), 0, stream>>>(bsums, nbN);
    k_scan3<<<dim3(nbN), blk, 0, stream>>>(part, bsums, rowptr, N);
    k_finish_deg_i<<<dim3(nbN), blk, 0, stream>>>(cnt, dinv, selfw, N);
    k_scatter<<<dim3(nbE), blk, 0, stream>>>(src, dst, dinv, rowptr, fill, esrc, ewt, E);

    // ---- conversions ----
    {
        long nx = (long)N * 128;
        k_cvt<<<dim3((unsigned)((nx + 255) / 256)), blk, 0, stream>>>(x, xh, nx);
        k_tcvt<<<dim3((128 * 256 + 255) / 256), blk, 0, stream>>>(Wc1, Wc1t, 128, 256);
        k_tcvt<<<dim3((128 * 256 + 255) / 256), blk, 0, stream>>>(Wd1, Wd1t, 128, 256);
        k_tcvt<<<dim3((256 * 256 + 255) / 256), blk, 0, stream>>>(Wc2, Wc2t, 256, 256);
        k_tcvt<<<dim3((256 * 256 + 255) / 256), blk, 0, stream>>>(Wd2, Wd2t, 256, 256);
        k_tcvt<<<dim3((256 * 256 + 255) / 256), blk, 0, stream>>>(Wc3, Wc3t, 256, 256);
        k_tcvt<<<dim3((256 * 256 + 255) / 256), blk, 0, stream>>>(Wd3, Wd3t, 256, 256);
        k_tcvt<<<dim3((256 * 128 + 255) / 256), blk, 0, stream>>>(Wp1, Wp1t, 256, 128);
        k_tcvt<<<dim3((128 * 256 + 255) / 256), blk, 0, stream>>>(Wp2, Wp2t, 128, 256);
    }

    const int ngb = (N + 3) / 4;
    const int nfb = (N + 63) / 64;

    // ---- static + temporal encoders (independent of GNN; stream-serial anyway) ----
    k_dense<<<dim3(4, B), blk, 0, stream>>>(sf, DS, Ws1, bs1, s1buf, 256, 0, DS, 256, 1);
    k_dense<<<dim3(4, B), blk, 0, stream>>>(s1buf, 256, Ws2, bs2, comb, 1280, 256, 256, 256, 0);
    k_dense<<<dim3(2, B), blk, 0, stream>>>(tf, 5, Wt1, bt1, t1buf, 128, 0, 5, 128, 1);
    k_dense<<<dim3(4, B), blk, 0, stream>>>(t1buf, 128, Wt2, bt2, comb, 1280, 512, 128, 256, 0);

    // ---- 3 GCN layers ----
    k_gather_b2<<<dim3(ngb), blk, 0, stream>>>(xh, rowptr, esrc, ewt, selfw, A, N, 128, 128);
    k_fused_mfma<<<dim3(nfb), blk, 0, stream>>>(A, xh, Wc1t, Wd1t, bc1, bd1, Bb, N, 128, 128, 128);
    k_gather_b4<<<dim3(ngb), blk, 0, stream>>>(Bb, rowptr, esrc, ewt, selfw, A, N, 256, 256);
    k_fused_mfma<<<dim3(nfb), blk, 0, stream>>>(A, Bb, Wc2t, Wd2t, bc2, bd2, A, N, 256, 256, 256);
    k_gather_b4<<<dim3(ngb), blk, 0, stream>>>(A, rowptr, esrc, ewt, selfw, Bb, N, 256, 256);
    k_fused_mfma<<<dim3(nfb), blk, 0, stream>>>(Bb, A, Wc3t, Wd3t, bc3, bd3, Bb, N, 256, 256, 256);

    // ---- pooling ranges + ge from x3 (Bb) ----
    k_ranges<<<dim3(1), dim3(128), 0, stream>>>(batch, N, B, startp, countsf);
    k_pool1b<<<dim3(B * 4), blk, 0, stream>>>(Bb, startp, countsf, ge);

    // ---- pattern detector + pe ----
    k_gemm_mfma<<<dim3((N + 127) / 128), blk, 0, stream>>>(Bb, Wp1t, bp1, A, N, 256, 128, 256, 1);
    k_gemm_mfma<<<dim3((N + 63) / 64), blk, 0, stream>>>(A, Wp2t, bp2, Bb, N, 128, 256, 128, 1);
    k_pool1b<<<dim3(B * 4), blk, 0, stream>>>(Bb, startp, countsf, pe);

    // ---- head: comb assembly -> fusion -> outputs (fp32, parallel per layer) ----
    k_comb<<<dim3(B), blk, 0, stream>>>(ge, pe, temb, tidx, comb);
    k_dense<<<dim3(8, B), blk, 0, stream>>>(comb, 1280, Wf1, bf1, fh, 512, 0, 1280, 512, 1);
    k_dense<<<dim3(4, B), blk, 0, stream>>>(fh, 512, Wf2, bf2, out_fused, 256, 0, 512, 256, 0);
    k_heads_small<<<dim3(B), blk, 0, stream>>>(out_fused, Wg, bg, Wtp, btp, out_logits, out_tp, NG);
}

// Round 7
// 897.709 us; speedup vs baseline: 12.7356x; 1.2465x over previous
//
#include <hip/hip_runtime.h>

#define H 256
#define LDK 40  // padded k-stride (halves): 80B rows -> <=2-way LDS bank aliasing (free)

typedef __attribute__((ext_vector_type(8))) short bf16x8;
typedef __attribute__((ext_vector_type(4))) float f32x4;

__device__ __forceinline__ float b2f(ushort h) {
    return __uint_as_float(((unsigned)h) << 16);
}
__device__ __forceinline__ ushort f2bf(float f) {
    unsigned u = __float_as_uint(f);
    unsigned r = (u + 0x7FFF + ((u >> 16) & 1)) >> 16;  // RNE
    return (ushort)r;
}

// ---------------- CSR build ----------------
__global__ __launch_bounds__(256) void k_zero_i(int* p, int n) {
    int i = blockIdx.x * 256 + threadIdx.x;
    if (i < n) p[i] = 0;
}

__global__ __launch_bounds__(256) void k_zero_f(float* p, int n) {
    int i = blockIdx.x * 256 + threadIdx.x;
    if (i < n) p[i] = 0.f;
}

__global__ __launch_bounds__(256) void k_count_deg_i(const int* __restrict__ dst, int* cnt, int E) {
    int i = blockIdx.x * 256 + threadIdx.x;
    if (i < E) atomicAdd(&cnt[dst[i]], 1);
}

__global__ __launch_bounds__(256) void k_scan1(const int* __restrict__ cnt, int* __restrict__ partial,
                                               int* __restrict__ bsums, int N) {
    __shared__ int s[256];
    int t = threadIdx.x;
    int idx = blockIdx.x * 256 + t;
    int v = idx < N ? cnt[idx] : 0;
    s[t] = v;
    __syncthreads();
    for (int off = 1; off < 256; off <<= 1) {
        int add = (t >= off) ? s[t - off] : 0;
        __syncthreads();
        s[t] += add;
        __syncthreads();
    }
    if (idx < N) partial[idx] = s[t];
    if (t == 255) bsums[blockIdx.x] = s[t];
}

__global__ __launch_bounds__(1024) void k_scan2(int* bsums, int nb) {
    __shared__ int s[1024];
    int t = threadIdx.x;
    s[t] = (t < nb) ? bsums[t] : 0;
    __syncthreads();
    for (int off = 1; off < 1024; off <<= 1) {
        int add = (t >= off) ? s[t - off] : 0;
        __syncthreads();
        s[t] += add;
        __syncthreads();
    }
    if (t < nb) bsums[t] = s[t];
}

__global__ __launch_bounds__(256) void k_scan3(const int* __restrict__ partial, const int* __restrict__ bsums,
                                               int* __restrict__ rowptr, int N) {
    int idx = blockIdx.x * 256 + threadIdx.x;
    if (idx < N) {
        int off = blockIdx.x > 0 ? bsums[blockIdx.x - 1] : 0;
        rowptr[idx + 1] = partial[idx] + off;
        if (idx == 0) rowptr[0] = 0;
    }
}

__global__ __launch_bounds__(256) void k_finish_deg_i(const int* __restrict__ cnt,
                                                      float* __restrict__ dinv,
                                                      float* __restrict__ selfw, int N) {
    int i = blockIdx.x * 256 + threadIdx.x;
    if (i < N) {
        float d = 1.0f + (float)cnt[i];
        dinv[i] = rsqrtf(d);
        selfw[i] = 1.0f / d;
    }
}

__global__ __launch_bounds__(256) void k_scatter(const int* __restrict__ src, const int* __restrict__ dst,
                                                 const float* __restrict__ dinv, const int* __restrict__ rowptr,
                                                 int* __restrict__ fill, int* __restrict__ esrc,
                                                 float* __restrict__ ewt, int E) {
    int e = blockIdx.x * 256 + threadIdx.x;
    if (e >= E) return;
    int s = src[e], d = dst[e];
    int pos = rowptr[d] + atomicAdd(&fill[d], 1);
    esrc[pos] = s;
    ewt[pos] = dinv[s] * dinv[d];
}

// ---------------- conversions ----------------
__global__ __launch_bounds__(256) void k_cvt(const float* __restrict__ in, ushort* __restrict__ out, long n) {
    long i = (long)blockIdx.x * 256 + threadIdx.x;
    if (i < n) out[i] = f2bf(in[i]);
}

__global__ __launch_bounds__(256) void k_tcvt(const float* __restrict__ W, ushort* __restrict__ Wt,
                                              int K, int M) {
    int idx = blockIdx.x * 256 + threadIdx.x;
    if (idx >= K * M) return;
    int k = idx / M, m = idx - k * M;
    Wt[(size_t)m * K + k] = f2bf(W[idx]);
}

// ---------------- CSR gather (bf16 in, fp32 acc, bf16 out) ----------------
__global__ __launch_bounds__(256) void k_gather_b4(const ushort* __restrict__ xin, const int* __restrict__ rowptr,
                                                   const int* __restrict__ esrc, const float* __restrict__ ewt,
                                                   const float* __restrict__ selfw, ushort* __restrict__ p,
                                                   int N, int SX, int SP) {
    int node = blockIdx.x * 4 + (threadIdx.x >> 6);
    if (node >= N) return;
    int c = (threadIdx.x & 63) << 2;
    ushort4 h = *(const ushort4*)(xin + (size_t)node * SX + c);
    float sw = selfw[node];
    float a0 = b2f(h.x) * sw, a1 = b2f(h.y) * sw, a2 = b2f(h.z) * sw, a3 = b2f(h.w) * sw;
    int j = rowptr[node], r1 = rowptr[node + 1];
    for (; j + 3 < r1; j += 4) {
        int s0 = esrc[j], s1 = esrc[j + 1], s2 = esrc[j + 2], s3 = esrc[j + 3];
        float w0 = ewt[j], w1 = ewt[j + 1], w2 = ewt[j + 2], w3 = ewt[j + 3];
        ushort4 v0 = *(const ushort4*)(xin + (size_t)s0 * SX + c);
        ushort4 v1 = *(const ushort4*)(xin + (size_t)s1 * SX + c);
        ushort4 v2 = *(const ushort4*)(xin + (size_t)s2 * SX + c);
        ushort4 v3 = *(const ushort4*)(xin + (size_t)s3 * SX + c);
        a0 += b2f(v0.x) * w0 + b2f(v1.x) * w1 + b2f(v2.x) * w2 + b2f(v3.x) * w3;
        a1 += b2f(v0.y) * w0 + b2f(v1.y) * w1 + b2f(v2.y) * w2 + b2f(v3.y) * w3;
        a2 += b2f(v0.z) * w0 + b2f(v1.z) * w1 + b2f(v2.z) * w2 + b2f(v3.z) * w3;
        a3 += b2f(v0.w) * w0 + b2f(v1.w) * w1 + b2f(v2.w) * w2 + b2f(v3.w) * w3;
    }
    for (; j < r1; ++j) {
        int s0 = esrc[j];
        float w0 = ewt[j];
        ushort4 v0 = *(const ushort4*)(xin + (size_t)s0 * SX + c);
        a0 += b2f(v0.x) * w0; a1 += b2f(v0.y) * w0; a2 += b2f(v0.z) * w0; a3 += b2f(v0.w) * w0;
    }
    ushort4 o;
    o.x = f2bf(a0); o.y = f2bf(a1); o.z = f2bf(a2); o.w = f2bf(a3);
    *(ushort4*)(p + (size_t)node * SP + c) = o;
}

__global__ __launch_bounds__(256) void k_gather_b2(const ushort* __restrict__ xin, const int* __restrict__ rowptr,
                                                   const int* __restrict__ esrc, const float* __restrict__ ewt,
                                                   const float* __restrict__ selfw, ushort* __restrict__ p,
                                                   int N, int SX, int SP) {
    int node = blockIdx.x * 4 + (threadIdx.x >> 6);
    if (node >= N) return;
    int c = (threadIdx.x & 63) << 1;
    ushort2 h = *(const ushort2*)(xin + (size_t)node * SX + c);
    float sw = selfw[node];
    float a0 = b2f(h.x) * sw, a1 = b2f(h.y) * sw;
    int j = rowptr[node], r1 = rowptr[node + 1];
    for (; j + 3 < r1; j += 4) {
        int s0 = esrc[j], s1 = esrc[j + 1], s2 = esrc[j + 2], s3 = esrc[j + 3];
        float w0 = ewt[j], w1 = ewt[j + 1], w2 = ewt[j + 2], w3 = ewt[j + 3];
        ushort2 v0 = *(const ushort2*)(xin + (size_t)s0 * SX + c);
        ushort2 v1 = *(const ushort2*)(xin + (size_t)s1 * SX + c);
        ushort2 v2 = *(const ushort2*)(xin + (size_t)s2 * SX + c);
        ushort2 v3 = *(const ushort2*)(xin + (size_t)s3 * SX + c);
        a0 += b2f(v0.x) * w0 + b2f(v1.x) * w1 + b2f(v2.x) * w2 + b2f(v3.x) * w3;
        a1 += b2f(v0.y) * w0 + b2f(v1.y) * w1 + b2f(v2.y) * w2 + b2f(v3.y) * w3;
    }
    for (; j < r1; ++j) {
        int s0 = esrc[j];
        float w0 = ewt[j];
        ushort2 v0 = *(const ushort2*)(xin + (size_t)s0 * SX + c);
        a0 += b2f(v0.x) * w0; a1 += b2f(v0.y) * w0;
    }
    ushort2 o;
    o.x = f2bf(a0); o.y = f2bf(a1);
    *(ushort2*)(p + (size_t)node * SP + c) = o;
}

// ---------------- fused dual-GEMM MFMA:  Out = relu(Pm@Wc + bc) + X@Wd + bd ----------------
__global__ __launch_bounds__(256, 2) void k_fused_mfma(
    const ushort* __restrict__ Pm, const ushort* __restrict__ X,
    const ushort* __restrict__ Wct, const ushort* __restrict__ Wdt,
    const float* __restrict__ bc, const float* __restrict__ bd,
    ushort* __restrict__ Out, int N, int K, int SP, int SX) {
    __shared__ short Ps[64 * LDK];
    __shared__ short Xs[64 * LDK];
    __shared__ short Wcs[256 * LDK];
    __shared__ short Wds[256 * LDK];
    const int tid = threadIdx.x;
    const int wave = tid >> 6, lane = tid & 63;
    const int row0 = blockIdx.x * 64;

    f32x4 accC[4][4], accD[4][4];
#pragma unroll
    for (int i = 0; i < 4; ++i)
#pragma unroll
        for (int j = 0; j < 4; ++j) { accC[i][j] = (f32x4)0.f; accD[i][j] = (f32x4)0.f; }

    const int sr = tid >> 2, sc = (tid & 3) * 8;
    int grow = row0 + sr; if (grow > N - 1) grow = N - 1;
    const int m = lane & 15, kh = (lane >> 4) * 8;

    for (int k0 = 0; k0 < K; k0 += 32) {
        *(uint4*)&Ps[sr * LDK + sc] = *(const uint4*)(Pm + (size_t)grow * SP + k0 + sc);
        *(uint4*)&Xs[sr * LDK + sc] = *(const uint4*)(X + (size_t)grow * SX + k0 + sc);
#pragma unroll
        for (int p = 0; p < 4; ++p) {
            int col = p * 64 + (tid >> 2);
            *(uint4*)&Wcs[col * LDK + sc] = *(const uint4*)(Wct + (size_t)col * K + k0 + sc);
            *(uint4*)&Wds[col * LDK + sc] = *(const uint4*)(Wdt + (size_t)col * K + k0 + sc);
        }
        __syncthreads();
        bf16x8 aP[4], aX[4], bC[4], bD[4];
#pragma unroll
        for (int i = 0; i < 4; ++i) {
            aP[i] = *(bf16x8*)&Ps[(16 * i + m) * LDK + kh];
            aX[i] = *(bf16x8*)&Xs[(16 * i + m) * LDK + kh];
        }
#pragma unroll
        for (int j = 0; j < 4; ++j) {
            int c = wave * 64 + 16 * j + m;
            bC[j] = *(bf16x8*)&Wcs[c * LDK + kh];
            bD[j] = *(bf16x8*)&Wds[c * LDK + kh];
        }
#pragma unroll
        for (int i = 0; i < 4; ++i)
#pragma unroll
            for (int j = 0; j < 4; ++j) {
                accC[i][j] = __builtin_amdgcn_mfma_f32_16x16x32_bf16(aP[i], bC[j], accC[i][j], 0, 0, 0);
                accD[i][j] = __builtin_amdgcn_mfma_f32_16x16x32_bf16(aX[i], bD[j], accD[i][j], 0, 0, 0);
            }
        __syncthreads();
    }

    const int rq = (lane >> 4) * 4;
#pragma unroll
    for (int j = 0; j < 4; ++j) {
        int col = wave * 64 + 16 * j + m;
        float bcv = bc[col], bdv = bd[col];
#pragma unroll
        for (int i = 0; i < 4; ++i)
#pragma unroll
            for (int g = 0; g < 4; ++g) {
                int row = row0 + 16 * i + rq + g;
                if (row < N) {
                    float v = fmaxf(accC[i][j][g] + bcv, 0.f) + accD[i][j][g] + bdv;
                    Out[(size_t)row * 256 + col] = f2bf(v);
                }
            }
    }
}

// ---------------- single-GEMM MFMA:  Out = [relu](A@W + b) ----------------
__global__ __launch_bounds__(256, 2) void k_gemm_mfma(
    const ushort* __restrict__ A, const ushort* __restrict__ Wt, const float* __restrict__ bias,
    ushort* __restrict__ Out, int N, int K, int M, int SA, int dorelu) {
    __shared__ short As[128 * LDK];
    __shared__ short Wls[256 * LDK];
    const int tid = threadIdx.x;
    const int wave = tid >> 6, lane = tid & 63;
    const int MW = M >> 6;
    const int R = 16384 / M;
    const int row0 = blockIdx.x * R;
    const int row_off = (wave / MW) * 64, col_off = (wave % MW) * 64;

    f32x4 acc[4][4];
#pragma unroll
    for (int i = 0; i < 4; ++i)
#pragma unroll
        for (int j = 0; j < 4; ++j) acc[i][j] = (f32x4)0.f;

    const int m = lane & 15, kh = (lane >> 4) * 8, sc = (tid & 3) * 8;

    for (int k0 = 0; k0 < K; k0 += 32) {
        for (int c = tid; c < R * 4; c += 256) {
            int r = c >> 2, ck = (c & 3) * 8;
            int gr = row0 + r; if (gr > N - 1) gr = N - 1;
            *(uint4*)&As[r * LDK + ck] = *(const uint4*)(A + (size_t)gr * SA + k0 + ck);
        }
        for (int p = 0; p < MW; ++p) {
            int col = p * 64 + (tid >> 2);
            *(uint4*)&Wls[col * LDK + sc] = *(const uint4*)(Wt + (size_t)col * K + k0 + sc);
        }
        __syncthreads();
        bf16x8 af[4], bf[4];
#pragma unroll
        for (int i = 0; i < 4; ++i) af[i] = *(bf16x8*)&As[(row_off + 16 * i + m) * LDK + kh];
#pragma unroll
        for (int j = 0; j < 4; ++j) bf[j] = *(bf16x8*)&Wls[(col_off + 16 * j + m) * LDK + kh];
#pragma unroll
        for (int i = 0; i < 4; ++i)
#pragma unroll
            for (int j = 0; j < 4; ++j)
                acc[i][j] = __builtin_amdgcn_mfma_f32_16x16x32_bf16(af[i], bf[j], acc[i][j], 0, 0, 0);
        __syncthreads();
    }

    const int rq = (lane >> 4) * 4;
#pragma unroll
    for (int j = 0; j < 4; ++j) {
        int col = col_off + 16 * j + m;
        float bv = bias[col];
#pragma unroll
        for (int i = 0; i < 4; ++i)
#pragma unroll
            for (int g = 0; g < 4; ++g) {
                int row = row0 + row_off + 16 * i + rq + g;
                if (row < N) {
                    float v = acc[i][j][g] + bv;
                    if (dorelu) v = fmaxf(v, 0.f);
                    Out[(size_t)row * M + col] = f2bf(v);
                }
            }
    }
}

// ---------------- pattern layer 2 + pooled epilogue (no pat materialization) ----------------
// per 64-row block: v = relu(A@Wt + bias) (M=256); reduce rows per graph segment, atomicAdd to pesum.
__global__ __launch_bounds__(256, 2) void k_pat2_pool(
    const ushort* __restrict__ A, const ushort* __restrict__ Wt, const float* __restrict__ bias,
    const int* __restrict__ batch, float* __restrict__ pesum, int N, int K, int SA) {
    __shared__ short As[64 * LDK];
    __shared__ short Wls[256 * LDK];
    __shared__ int sbatch[64];
    const int tid = threadIdx.x;
    const int wave = tid >> 6, lane = tid & 63;
    const int row0 = blockIdx.x * 64;
    const int col_off = wave * 64;

    f32x4 acc[4][4];
#pragma unroll
    for (int i = 0; i < 4; ++i)
#pragma unroll
        for (int j = 0; j < 4; ++j) acc[i][j] = (f32x4)0.f;

    const int m = lane & 15, kh = (lane >> 4) * 8, sc = (tid & 3) * 8;
    if (tid < 64) {
        int r = row0 + tid;
        sbatch[tid] = batch[r < N ? r : (N - 1)];
    }

    for (int k0 = 0; k0 < K; k0 += 32) {
        {
            int r = tid >> 2, ck = (tid & 3) * 8;
            int gr = row0 + r; if (gr > N - 1) gr = N - 1;
            *(uint4*)&As[r * LDK + ck] = *(const uint4*)(A + (size_t)gr * SA + k0 + ck);
        }
#pragma unroll
        for (int p = 0; p < 4; ++p) {
            int col = p * 64 + (tid >> 2);
            *(uint4*)&Wls[col * LDK + sc] = *(const uint4*)(Wt + (size_t)col * K + k0 + sc);
        }
        __syncthreads();
        bf16x8 af[4], bf[4];
#pragma unroll
        for (int i = 0; i < 4; ++i) af[i] = *(bf16x8*)&As[(16 * i + m) * LDK + kh];
#pragma unroll
        for (int j = 0; j < 4; ++j) bf[j] = *(bf16x8*)&Wls[(col_off + 16 * j + m) * LDK + kh];
#pragma unroll
        for (int i = 0; i < 4; ++i)
#pragma unroll
            for (int j = 0; j < 4; ++j)
                acc[i][j] = __builtin_amdgcn_mfma_f32_16x16x32_bf16(af[i], bf[j], acc[i][j], 0, 0, 0);
        __syncthreads();
    }

    const int rq = (lane >> 4) * 4;
    const int g0 = sbatch[0];
    const int g1 = sbatch[63];
    for (int g = g0; g <= g1; ++g) {
#pragma unroll
        for (int j = 0; j < 4; ++j) {
            float bv = bias[col_off + 16 * j + m];
            float s = 0.f;
#pragma unroll
            for (int i = 0; i < 4; ++i)
#pragma unroll
                for (int q = 0; q < 4; ++q) {
                    int rl = 16 * i + rq + q;
                    bool ok = (sbatch[rl] == g) && (row0 + rl < N);
                    float v = fmaxf(acc[i][j][q] + bv, 0.f);
                    s += ok ? v : 0.f;
                }
            s += __shfl_down(s, 32, 64);
            s += __shfl_down(s, 16, 64);
            if (lane < 16) atomicAdd(&pesum[(size_t)g * 256 + col_off + 16 * j + lane], s);
        }
    }
}

// ---------------- pooling ----------------
__global__ void k_ranges(const int* __restrict__ batch, int N, int B, int* __restrict__ start,
                         float* __restrict__ countsf) {
    int b = threadIdx.x;
    if (b <= B) {
        int lo = 0, hi = N;
        while (lo < hi) {
            int mid = (lo + hi) >> 1;
            if (batch[mid] < b) lo = mid + 1; else hi = mid;
        }
        start[b] = lo;
    }
    __syncthreads();
    if (b < B) {
        int cnt = start[b + 1] - start[b];
        countsf[b] = (float)(cnt > 0 ? cnt : 1);
    }
}

// phase-1 mean-pool: grid (B, S). Wave reads full 256-col rows (ushort4/lane); LDS reduce; atomicAdd.
#define POOLS 16
__global__ __launch_bounds__(256) void k_pool2(const ushort* __restrict__ M_, const int* __restrict__ start,
                                               float* __restrict__ outsum) {
    int b = blockIdx.x;
    int s = blockIdx.y;
    int wave = threadIdx.x >> 6, lane = threadIdx.x & 63;
    int r0 = start[b], r1 = start[b + 1];
    int stripe = s * 4 + wave;
    float a0 = 0.f, a1 = 0.f, a2 = 0.f, a3 = 0.f;
    for (int r = r0 + stripe; r < r1; r += POOLS * 4) {
        ushort4 v = *(const ushort4*)(M_ + (size_t)r * 256 + lane * 4);
        a0 += b2f(v.x); a1 += b2f(v.y); a2 += b2f(v.z); a3 += b2f(v.w);
    }
    __shared__ float red[4][256];
    *(float4*)&red[wave][lane * 4] = make_float4(a0, a1, a2, a3);
    __syncthreads();
    int col = threadIdx.x;
    float t = red[0][col] + red[1][col] + red[2][col] + red[3][col];
    if (t != 0.f) atomicAdd(&outsum[(size_t)b * 256 + col], t);
}

// finalize: divide sums by counts (ge and pe)
__global__ __launch_bounds__(256) void k_pool_fin(float* __restrict__ ge, float* __restrict__ pe,
                                                  const float* __restrict__ countsf) {
    int b = blockIdx.x, t = threadIdx.x;
    float inv = 1.0f / countsf[b];
    ge[(size_t)b * 256 + t] *= inv;
    pe[(size_t)b * 256 + t] *= inv;
}

// ---------------- head: parallel fp32 dense layer ----------------
__global__ __launch_bounds__(256) void k_dense(const float* __restrict__ vin, int vs,
                                               const float* __restrict__ W, const float* __restrict__ bias,
                                               float* __restrict__ out, int os, int oo,
                                               int K, int M, int relu) {
    const int b = blockIdx.y;
    const int wave = threadIdx.x >> 6, lane = threadIdx.x & 63;
    const int c = blockIdx.x * 64 + lane;
    const float* vrow = vin + (size_t)b * vs;
    float acc = 0.f;
    int k = wave;
    for (; k + 28 < K; k += 32) {
#pragma unroll
        for (int u = 0; u < 8; ++u)
            acc += vrow[k + 4 * u] * W[(size_t)(k + 4 * u) * M + c];
    }
    for (; k < K; k += 4)
        acc += vrow[k] * W[(size_t)k * M + c];
    __shared__ float red[4][64];
    red[wave][lane] = acc;
    __syncthreads();
    if (wave == 0) {
        float s = red[0][lane] + red[1][lane] + red[2][lane] + red[3][lane] + bias[c];
        if (relu) s = fmaxf(s, 0.f);
        out[(size_t)b * os + oo + c] = s;
    }
}

__global__ __launch_bounds__(256) void k_comb(const float* __restrict__ ge, const float* __restrict__ pe,
                                              const float* __restrict__ temb, const int* __restrict__ tidx,
                                              float* __restrict__ comb) {
    int b = blockIdx.x, t = threadIdx.x;
    float* o = comb + (size_t)b * 1280;
    o[t] = ge[(size_t)b * 256 + t];
    o[768 + t] = temb[(size_t)tidx[b] * 256 + t];
    o[1024 + t] = pe[(size_t)b * 256 + t];
}

__global__ __launch_bounds__(256) void k_heads_small(const float* __restrict__ fused,
                                                     const float* __restrict__ Wg, const float* __restrict__ bg,
                                                     const float* __restrict__ Wtp, const float* __restrict__ btp,
                                                     float* __restrict__ out_logits, float* __restrict__ out_tp,
                                                     int NG) {
    __shared__ float lf[256];
    int b = blockIdx.x, tid = threadIdx.x;
    int wave = tid >> 6, lane = tid & 63;
    lf[tid] = fused[(size_t)b * 256 + tid];
    __syncthreads();
    for (int c = wave; c < NG; c += 4) {
        float s = 0.f;
#pragma unroll
        for (int k = lane; k < 256; k += 64) s += lf[k] * Wg[(size_t)k * NG + c];
#pragma unroll
        for (int off = 32; off > 0; off >>= 1) s += __shfl_down(s, off, 64);
        if (lane == 0) out_logits[(size_t)b * NG + c] = s + bg[c];
    }
    if (wave == 0) {
        float s = 0.f;
#pragma unroll
        for (int k = lane; k < 256; k += 64) s += lf[k] * Wtp[k];
#pragma unroll
        for (int off = 32; off > 0; off >>= 1) s += __shfl_down(s, off, 64);
        if (lane == 0) out_tp[b] = s + btp[0];
    }
}

// ---------------- host launch ----------------
extern "C" void kernel_launch(void* const* d_in, const int* in_sizes, int n_in,
                              void* d_out, int out_size, void* d_ws, size_t ws_size,
                              hipStream_t stream) {
    const float* x   = (const float*)d_in[0];
    const int* ei    = (const int*)d_in[1];
    const int* batch = (const int*)d_in[2];
    const float* sf  = (const float*)d_in[3];
    const float* tf  = (const float*)d_in[4];
    const int* tidx  = (const int*)d_in[5];
    const float* temb = (const float*)d_in[6];
    const float *Ws1 = (const float*)d_in[7],  *bs1 = (const float*)d_in[8];
    const float *Ws2 = (const float*)d_in[9],  *bs2 = (const float*)d_in[10];
    const float *Wc1 = (const float*)d_in[11], *bc1 = (const float*)d_in[12];
    const float *Wc2 = (const float*)d_in[13], *bc2 = (const float*)d_in[14];
    const float *Wc3 = (const float*)d_in[15], *bc3 = (const float*)d_in[16];
    const float *Wd1 = (const float*)d_in[17], *bd1 = (const float*)d_in[18];
    const float *Wd2 = (const float*)d_in[19], *bd2 = (const float*)d_in[20];
    const float *Wd3 = (const float*)d_in[21], *bd3 = (const float*)d_in[22];
    const float *Wt1 = (const float*)d_in[23], *bt1 = (const float*)d_in[24];
    const float *Wt2 = (const float*)d_in[25], *bt2 = (const float*)d_in[26];
    const float *Wp1 = (const float*)d_in[27], *bp1 = (const float*)d_in[28];
    const float *Wp2 = (const float*)d_in[29], *bp2 = (const float*)d_in[30];
    const float *Wf1 = (const float*)d_in[31], *bf1 = (const float*)d_in[32];
    const float *Wf2 = (const float*)d_in[33], *bf2 = (const float*)d_in[34];
    const float *Wg  = (const float*)d_in[35], *bg  = (const float*)d_in[36];
    const float *Wtp = (const float*)d_in[37], *btp = (const float*)d_in[38];

    const int N = in_sizes[2];
    const int E = in_sizes[1] / 2;
    const int B = in_sizes[5];
    const int DS = in_sizes[3] / B;        // 1024
    const int NG = in_sizes[36];           // 20
    const int* src = ei;
    const int* dst = ei + E;

    // ---- workspace layout ----
    char* w = (char*)d_ws;
    ushort* A   = (ushort*)w;              w += (size_t)N * 256 * 2;
    ushort* Bb  = (ushort*)w;              w += (size_t)N * 256 * 2;
    ushort* xh  = (ushort*)w;              w += (size_t)N * 128 * 2;
    ushort* Wc1t = (ushort*)w;             w += 128 * 256 * 2;
    ushort* Wd1t = (ushort*)w;             w += 128 * 256 * 2;
    ushort* Wc2t = (ushort*)w;             w += 256 * 256 * 2;
    ushort* Wd2t = (ushort*)w;             w += 256 * 256 * 2;
    ushort* Wc3t = (ushort*)w;             w += 256 * 256 * 2;
    ushort* Wd3t = (ushort*)w;             w += 256 * 256 * 2;
    ushort* Wp1t = (ushort*)w;             w += 256 * 128 * 2;
    ushort* Wp2t = (ushort*)w;             w += 128 * 256 * 2;
    int* esrc   = (int*)w;                 w += (size_t)E * 4;
    float* ewt  = (float*)w;               w += (size_t)E * 4;
    int* cnt    = (int*)w;                 w += (size_t)N * 4;
    int* part   = (int*)w;                 w += (size_t)N * 4;
    int* rowptr = (int*)w;                 w += (size_t)(N + 1) * 4;
    int* fill   = (int*)w;                 w += (size_t)N * 4;
    int* bsums  = (int*)w;                 w += 1024 * 4;
    float* dinv = (float*)w;               w += (size_t)N * 4;
    float* selfw = (float*)w;              w += (size_t)N * 4;
    int* startp = (int*)w;                 w += (B + 1) * 4;
    float* countsf = (float*)w;            w += B * 4;
    float* ge = (float*)w;                 w += B * 256 * 4;   // ge then pe contiguous (zeroed together)
    float* pe = (float*)w;                 w += B * 256 * 4;
    float* s1buf = (float*)w;              w += B * 256 * 4;
    float* t1buf = (float*)w;              w += B * 128 * 4;
    float* comb = (float*)w;               w += B * 1280 * 4;
    float* fh = (float*)w;                 w += B * 512 * 4;

    float* out_fused = (float*)d_out;                 // B x 256
    float* out_logits = out_fused + (size_t)B * H;    // B x NG
    float* out_tp = out_logits + (size_t)B * NG;      // B x 1

    dim3 blk(256);
    const int nbN = (N + 255) / 256;
    const int nbE = (E + 255) / 256;

    // ---- CSR build ----
    k_zero_i<<<dim3(nbN), blk, 0, stream>>>(cnt, N);
    k_zero_i<<<dim3(nbN), blk, 0, stream>>>(fill, N);
    k_count_deg_i<<<dim3(nbE), blk, 0, stream>>>(dst, cnt, E);
    k_scan1<<<dim3(nbN), blk, 0, stream>>>(cnt, part, bsums, N);
    k_scan2<<<dim3(1), dim3(1024), 0, stream>>>(bsums, nbN);
    k_scan3<<<dim3(nbN), blk, 0, stream>>>(part, bsums, rowptr, N);
    k_finish_deg_i<<<dim3(nbN), blk, 0, stream>>>(cnt, dinv, selfw, N);
    k_scatter<<<dim3(nbE), blk, 0, stream>>>(src, dst, dinv, rowptr, fill, esrc, ewt, E);

    // ---- conversions + pooling prep ----
    {
        long nx = (long)N * 128;
        k_cvt<<<dim3((unsigned)((nx + 255) / 256)), blk, 0, stream>>>(x, xh, nx);
        k_tcvt<<<dim3((128 * 256 + 255) / 256), blk, 0, stream>>>(Wc1, Wc1t, 128, 256);
        k_tcvt<<<dim3((128 * 256 + 255) / 256), blk, 0, stream>>>(Wd1, Wd1t, 128, 256);
        k_tcvt<<<dim3((256 * 256 + 255) / 256), blk, 0, stream>>>(Wc2, Wc2t, 256, 256);
        k_tcvt<<<dim3((256 * 256 + 255) / 256), blk, 0, stream>>>(Wd2, Wd2t, 256, 256);
        k_tcvt<<<dim3((256 * 256 + 255) / 256), blk, 0, stream>>>(Wc3, Wc3t, 256, 256);
        k_tcvt<<<dim3((256 * 256 + 255) / 256), blk, 0, stream>>>(Wd3, Wd3t, 256, 256);
        k_tcvt<<<dim3((256 * 128 + 255) / 256), blk, 0, stream>>>(Wp1, Wp1t, 256, 128);
        k_tcvt<<<dim3((128 * 256 + 255) / 256), blk, 0, stream>>>(Wp2, Wp2t, 128, 256);
        k_ranges<<<dim3(1), dim3(128), 0, stream>>>(batch, N, B, startp, countsf);
        k_zero_f<<<dim3((2 * B * 256 + 255) / 256), blk, 0, stream>>>(ge, 2 * B * 256);
    }

    const int ngb = (N + 3) / 4;
    const int nfb = (N + 63) / 64;

    // ---- static + temporal encoders ----
    k_dense<<<dim3(4, B), blk, 0, stream>>>(sf, DS, Ws1, bs1, s1buf, 256, 0, DS, 256, 1);
    k_dense<<<dim3(4, B), blk, 0, stream>>>(s1buf, 256, Ws2, bs2, comb, 1280, 256, 256, 256, 0);
    k_dense<<<dim3(2, B), blk, 0, stream>>>(tf, 5, Wt1, bt1, t1buf, 128, 0, 5, 128, 1);
    k_dense<<<dim3(4, B), blk, 0, stream>>>(t1buf, 128, Wt2, bt2, comb, 1280, 512, 128, 256, 0);

    // ---- 3 GCN layers ----
    k_gather_b2<<<dim3(ngb), blk, 0, stream>>>(xh, rowptr, esrc, ewt, selfw, A, N, 128, 128);
    k_fused_mfma<<<dim3(nfb), blk, 0, stream>>>(A, xh, Wc1t, Wd1t, bc1, bd1, Bb, N, 128, 128, 128);
    k_gather_b4<<<dim3(ngb), blk, 0, stream>>>(Bb, rowptr, esrc, ewt, selfw, A, N, 256, 256);
    k_fused_mfma<<<dim3(nfb), blk, 0, stream>>>(A, Bb, Wc2t, Wd2t, bc2, bd2, A, N, 256, 256, 256);
    k_gather_b4<<<dim3(ngb), blk, 0, stream>>>(A, rowptr, esrc, ewt, selfw, Bb, N, 256, 256);
    k_fused_mfma<<<dim3(nfb), blk, 0, stream>>>(Bb, A, Wc3t, Wd3t, bc3, bd3, Bb, N, 256, 256, 256);

    // ---- ge = mean-pool(x3) via 2-phase; pattern: p1 GEMM then fused pat+pool for pe ----
    k_pool2<<<dim3(B, POOLS), blk, 0, stream>>>(Bb, startp, ge);
    k_gemm_mfma<<<dim3((N + 127) / 128), blk, 0, stream>>>(Bb, Wp1t, bp1, A, N, 256, 128, 256, 1);
    k_pat2_pool<<<dim3(nfb), blk, 0, stream>>>(A, Wp2t, bp2, batch, pe, N, 128, 128);
    k_pool_fin<<<dim3(B), blk, 0, stream>>>(ge, pe, countsf);

    // ---- head ----
    k_comb<<<dim3(B), blk, 0, stream>>>(ge, pe, temb, tidx, comb);
    k_dense<<<dim3(8, B), blk, 0, stream>>>(comb, 1280, Wf1, bf1, fh, 512, 0, 1280, 512, 1);
    k_dense<<<dim3(4, B), blk, 0, stream>>>(fh, 512, Wf2, bf2, out_fused, 256, 0, 512, 256, 0);
    k_heads_small<<<dim3(B), blk, 0, stream>>>(out_fused, Wg, bg, Wtp, btp, out_logits, out_tp, NG);
}